// Round 1
// baseline (824.141 us; speedup 1.0000x reference)
//
#include <hip/hip_runtime.h>
#include <math.h>

#define NN 4096
#define SS 2048
#define DD 128
#define NADJ 2
#define MAXNNZ 64

__device__ __forceinline__ float softplusf(float x) {
    if (x > 20.f) return x;
    if (x < -20.f) return expf(x);
    return log1pf(expf(x));
}

// ---------------- params + zero sums ----------------
__global__ void params_kernel(const float* rls, const float* rvw, const float* rsw,
                              const float* rsb, const float* rsa, const float* rta,
                              float* params, double* sums) {
    if (threadIdx.x == 0) {
        float ls = softplusf(rls[0]);
        float vw = softplusf(rvw[0]);
        float sw = softplusf(rsw[0]);
        float sb = softplusf(rsb[0]);
        float a0 = softplusf(rsa[0]) * softplusf(rta[0]);
        float a1 = softplusf(rsa[1]) * softplusf(rta[1]);
        float vw2 = vw * vw, sw2 = sw * sw, sb2 = sb * sb;
        params[0] = 1.f / ls;
        params[1] = vw2 * sb2 * (a0 + a1);  // c_add
        params[2] = vw2 * sw2 * a0;         // w0
        params[3] = vw2 * sw2 * a1;         // w1
        sums[0] = 0.0; sums[1] = 0.0; sums[2] = 0.0;
    }
}

// ---------------- squared norms of feat/ls ----------------
__global__ void sqnorm_kernel(const float* feat, const float* params, float* xn) {
    int r = blockIdx.x;
    int l = threadIdx.x;  // 64 lanes
    float inv_ls = params[0];
    float v0 = feat[r * DD + l] * inv_ls;
    float v1 = feat[r * DD + 64 + l] * inv_ls;
    float s = v0 * v0 + v1 * v1;
    for (int off = 32; off; off >>= 1) s += __shfl_xor(s, off);
    if (l == 0) xn[r] = s;
}

// ---------------- C0 = exp(-0.5 * sqdist) , fp32 tiled matmul ----------------
__global__ __launch_bounds__(256) void c0_kernel(const float* feat, const float* params,
                                                 const float* xn, float* C0) {
    __shared__ float As[32][DD + 1];
    __shared__ float Bs[32][DD + 1];
    float inv_ls = params[0];
    int r0 = blockIdx.y * 32, c0 = blockIdx.x * 32;
    int t = threadIdx.x + threadIdx.y * 16;
    // load tiles (scalar LDS stores to keep padding; float4 global loads)
    for (int i = t; i < 32 * DD / 4; i += 256) {
        int row = (i * 4) / DD;
        int col = (i * 4) % DD;
        float4 a = *(const float4*)&feat[(size_t)(r0 + row) * DD + col];
        As[row][col + 0] = a.x * inv_ls;
        As[row][col + 1] = a.y * inv_ls;
        As[row][col + 2] = a.z * inv_ls;
        As[row][col + 3] = a.w * inv_ls;
        float4 b = *(const float4*)&feat[(size_t)(c0 + row) * DD + col];
        Bs[row][col + 0] = b.x * inv_ls;
        Bs[row][col + 1] = b.y * inv_ls;
        Bs[row][col + 2] = b.z * inv_ls;
        Bs[row][col + 3] = b.w * inv_ls;
    }
    __syncthreads();
    int tx = threadIdx.x, ty = threadIdx.y;
    float acc00 = 0.f, acc01 = 0.f, acc10 = 0.f, acc11 = 0.f;
    for (int k = 0; k < DD; k++) {
        float a0 = As[ty * 2 + 0][k], a1 = As[ty * 2 + 1][k];
        float b0 = Bs[tx * 2 + 0][k], b1 = Bs[tx * 2 + 1][k];
        acc00 += a0 * b0; acc01 += a0 * b1;
        acc10 += a1 * b0; acc11 += a1 * b1;
    }
    float accs[2][2] = {{acc00, acc01}, {acc10, acc11}};
    for (int i = 0; i < 2; i++)
        for (int j = 0; j < 2; j++) {
            int r = r0 + ty * 2 + i, c = c0 + tx * 2 + j;
            float sq = xn[r] + xn[c] - 2.f * accs[i][j];
            sq = fmaxf(sq, 0.f);
            C0[(size_t)r * NN + c] = expf(-0.5f * sq);
        }
}

// ---------------- CSR extraction (block-masked), deterministic ----------------
__global__ void extract_kernel(const float* adj, int* nnzc, int* colsa) {
    int b = blockIdx.x;        // i*NN + r
    int i = b >> 12;
    int r = b & (NN - 1);
    int lane = threadIdx.x;    // 64
    int base = (r < SS) ? 0 : SS;
    const float* arow = adj + ((size_t)i * NN + r) * NN + base;
    int* crow = colsa + (size_t)b * MAXNNZ;
    int cnt = 0;
    for (int it = 0; it < SS / 64; ++it) {
        int c = it * 64 + lane;
        float v = arow[c];
        unsigned long long m = __ballot(v != 0.f);
        if (v != 0.f) {
            int pos = cnt + __popcll(m & ((1ull << lane) - 1ull));
            if (pos < MAXNNZ) crow[pos] = base + c;
        }
        cnt += __popcll(m);
    }
    if (lane == 0) nnzc[b] = cnt > MAXNNZ ? MAXNNZ : cnt;
}

// ---------------- SpMM1: Tt_i = (A_i @ K)^T, transposed write ----------------
__global__ __launch_bounds__(256) void spmm1_kernel(const float* K, const int* nnzc,
                                                    const int* colsa, float* T0, float* T1) {
    __shared__ float tile[64][65];
    int i = blockIdx.z;
    int r0 = blockIdx.y * 64, c0 = blockIdx.x * 64;
    int t = threadIdx.x;
    int cl = t & 63, rg = t >> 6;  // rg in 0..3
    float* Tt = i ? T1 : T0;
    for (int j = 0; j < 16; ++j) {
        int rl = rg + 4 * j;
        int r = r0 + rl;
        int b = (i << 12) + r;
        int cnt = nnzc[b];
        const int* crow = colsa + (size_t)b * MAXNNZ;
        float acc = 0.f;
        for (int k = 0; k < cnt; k++) {
            int col = crow[k];
            acc += K[(size_t)col * NN + c0 + cl];
        }
        tile[rl][cl] = acc;
    }
    __syncthreads();
    for (int j = 0; j < 16; ++j) {
        int cl2 = rg + 4 * j;
        Tt[(size_t)(c0 + cl2) * NN + r0 + cl] = tile[cl][cl2];
    }
}

// ---------------- SpMM2: Kout = c_add + w0*A0@Tt0 + w1*A1@Tt1 ----------------
__global__ __launch_bounds__(256) void spmm2_kernel(const float* T0, const float* T1,
                                                    const int* nnzc, const int* colsa,
                                                    const float* params, float* Kout) {
    int r = blockIdx.y;
    int c = blockIdx.x * 1024 + threadIdx.x * 4;
    float c_add = params[1], w0 = params[2], w1 = params[3];
    float ax = 0.f, ay = 0.f, az = 0.f, aw = 0.f;
    float bx = 0.f, by = 0.f, bz = 0.f, bw = 0.f;
    {
        int b0 = r;
        int cnt = nnzc[b0];
        const int* crow = colsa + (size_t)b0 * MAXNNZ;
        for (int k = 0; k < cnt; k++) {
            float4 v = *(const float4*)&T0[(size_t)crow[k] * NN + c];
            ax += v.x; ay += v.y; az += v.z; aw += v.w;
        }
    }
    {
        int b1 = NN + r;
        int cnt = nnzc[b1];
        const int* crow = colsa + (size_t)b1 * MAXNNZ;
        for (int k = 0; k < cnt; k++) {
            float4 v = *(const float4*)&T1[(size_t)crow[k] * NN + c];
            bx += v.x; by += v.y; bz += v.z; bw += v.w;
        }
    }
    float4 o;
    o.x = c_add + w0 * ax + w1 * bx;
    o.y = c_add + w0 * ay + w1 * by;
    o.z = c_add + w0 * az + w1 * bz;
    o.w = c_add + w0 * aw + w1 * bw;
    *(float4*)&Kout[(size_t)r * NN + c] = o;
}

// ---------------- diag -> s = sqrt(diag)+1e-5 ----------------
__global__ void diag_kernel(const float* K, float* svec) {
    int r = blockIdx.x * 256 + threadIdx.x;
    if (r < NN) svec[r] = sqrtf(K[(size_t)r * NN + r]) + 1e-5f;
}

// ---------------- relu_cov in place ----------------
__global__ __launch_bounds__(256) void relu_kernel(float* K, const float* svec) {
    size_t idx = (size_t)blockIdx.x * 256 + threadIdx.x;  // float4 index
    int r = (int)(idx >> 10);
    int c4 = (int)(idx & 1023) << 2;
    const float PIF = 3.14159265358979323846f;
    const float INV2PI = 0.15915494309189535f;
    float sr = svec[r];
    float4 sc = *(const float4*)&svec[c4];
    float4 kv = *(float4*)&K[(size_t)r * NN + c4];
    float scs[4] = {sc.x, sc.y, sc.z, sc.w};
    float kvs[4] = {kv.x, kv.y, kv.z, kv.w};
    float out[4];
    for (int j = 0; j < 4; j++) {
        float p = sr * scs[j];
        float cc = kvs[j] / p;
        cc = fminf(fmaxf(cc, -1.f + 1e-6f), 1.f - 1e-6f);
        float th = acosf(cc);
        float sth = sqrtf(fmaxf(1.f - cc * cc, 0.f));
        out[j] = INV2PI * (sth + (PIF - th) * cc) * p;
    }
    float4 o = {out[0], out[1], out[2], out[3]};
    *(float4*)&K[(size_t)r * NN + c4] = o;
}

// ---------------- block sums (fp64 atomics) ----------------
__global__ __launch_bounds__(256) void sums_kernel(const float* K, double* sums) {
    double ss = 0.0, st = 0.0, tt = 0.0;
    size_t total = (size_t)NN * NN / 4;
    for (size_t idx = (size_t)blockIdx.x * 256 + threadIdx.x; idx < total;
         idx += (size_t)gridDim.x * 256) {
        int r = (int)(idx >> 10);
        int c4 = (int)(idx & 1023) << 2;
        float4 v = *(const float4*)&K[(size_t)r * NN + c4];
        double s4 = (double)v.x + (double)v.y + (double)v.z + (double)v.w;
        if (r < SS) {
            if (c4 < SS) ss += s4; else st += s4;
        } else if (c4 >= SS) tt += s4;
    }
    __shared__ double red[3 * 256];
    int t = threadIdx.x;
    red[t] = ss; red[256 + t] = st; red[512 + t] = tt;
    __syncthreads();
    for (int off = 128; off; off >>= 1) {
        if (t < off) {
            red[t] += red[t + off];
            red[256 + t] += red[256 + t + off];
            red[512 + t] += red[512 + t + off];
        }
        __syncthreads();
    }
    if (t == 0) {
        atomicAdd(&sums[0], red[0]);
        atomicAdd(&sums[1], red[256]);
        atomicAdd(&sums[2], red[512]);
    }
}

// ---------------- final: gather + index_K scale ----------------
__global__ __launch_bounds__(256) void final_kernel(const float* K, const int* x1, const int* x2,
                                                    const double* sums, float* out) {
    size_t idx = (size_t)blockIdx.x * 256 + threadIdx.x;  // quad index
    int i = (int)(idx >> 10);
    int j4 = (int)(idx & 1023) << 2;
    const double invc = 1.0 / ((double)SS * (double)SS);
    float mss = (float)(sums[0] * invc);
    float mst = (float)(sums[1] * invc);
    float mtt = (float)(sums[2] * invc);
    int row = x1[i];
    float o[4];
    for (int j = 0; j < 4; j++) {
        int col = x2[j4 + j];
        float v = K[(size_t)row * NN + col];
        float m = (row < SS) ? (col < SS ? mss : mst) : (col < SS ? mst : mtt);
        o[j] = v * m;
    }
    float4 ov = {o[0], o[1], o[2], o[3]};
    *(float4*)&out[(size_t)i * NN + j4] = ov;
}

extern "C" void kernel_launch(void* const* d_in, const int* in_sizes, int n_in,
                              void* d_out, int out_size, void* d_ws, size_t ws_size,
                              hipStream_t stream) {
    const float* feat = (const float*)d_in[0];
    const float* adj  = (const float*)d_in[1];
    const float* rls  = (const float*)d_in[2];
    const float* rvw  = (const float*)d_in[3];
    const float* rsw  = (const float*)d_in[4];
    const float* rsb  = (const float*)d_in[5];
    const float* rsa  = (const float*)d_in[6];
    const float* rta  = (const float*)d_in[7];
    const int*   x1   = (const int*)d_in[8];
    const int*   x2   = (const int*)d_in[9];
    float* out = (float*)d_out;

    const size_t PNN = (size_t)NN * NN;
    char* w = (char*)d_ws;
    float*  params = (float*)(w + 0);            // 16 floats
    double* sums   = (double*)(w + 64);          // 3 doubles
    float*  xn     = (float*)(w + 128);          // 16 KB
    float*  svec   = (float*)(w + 128 + 16384);  // 16 KB
    int*    nnzc   = (int*)(w + 128 + 32768);    // 32 KB
    int*    colsa  = (int*)(w + 128 + 65536);    // 2 MiB
    size_t  big0   = ((size_t)(128 + 65536) + (size_t)NADJ * NN * MAXNNZ * 4 + 255) & ~(size_t)255;
    float* bufK  = (float*)(w + big0);
    float* bufT0 = bufK + PNN;
    float* bufT1 = (ws_size >= big0 + 3 * PNN * 4) ? (bufT0 + PNN) : (float*)d_out;

    params_kernel<<<1, 64, 0, stream>>>(rls, rvw, rsw, rsb, rsa, rta, params, sums);
    sqnorm_kernel<<<NN, 64, 0, stream>>>(feat, params, xn);
    c0_kernel<<<dim3(NN / 32, NN / 32), dim3(16, 16), 0, stream>>>(feat, params, xn, bufK);
    extract_kernel<<<NADJ * NN, 64, 0, stream>>>(adj, nnzc, colsa);

    // layer 1: K1 = vw^2 * adj_conv(C0)
    spmm1_kernel<<<dim3(64, 64, 2), 256, 0, stream>>>(bufK, nnzc, colsa, bufT0, bufT1);
    spmm2_kernel<<<dim3(4, NN), 256, 0, stream>>>(bufT0, bufT1, nnzc, colsa, params, bufK);

    // relu_cov in place
    diag_kernel<<<16, 256, 0, stream>>>(bufK, svec);
    relu_kernel<<<16384, 256, 0, stream>>>(bufK, svec);

    // layer 2: K2 = vw^2 * adj_conv(relu_cov(K1))
    spmm1_kernel<<<dim3(64, 64, 2), 256, 0, stream>>>(bufK, nnzc, colsa, bufT0, bufT1);
    spmm2_kernel<<<dim3(4, NN), 256, 0, stream>>>(bufT0, bufT1, nnzc, colsa, params, bufK);

    // block means + final scale/gather
    sums_kernel<<<2048, 256, 0, stream>>>(bufK, sums);
    final_kernel<<<16384, 256, 0, stream>>>(bufK, x1, x2, sums, out);
}

// Round 2
// 749.266 us; speedup vs baseline: 1.0999x; 1.0999x over previous
//
#include <hip/hip_runtime.h>
#include <math.h>

#define NN 4096
#define SS 2048
#define DD 128
#define NADJ 2
#define MAXNNZ 64
#define CB 1024   // cols per passA block
#define JG 32     // rows per passA block

__device__ __forceinline__ float softplusf(float x) {
    if (x > 20.f) return x;
    if (x < -20.f) return expf(x);
    return log1pf(expf(x));
}

// ---------------- params + zero sums ----------------
__global__ void params_kernel(const float* rls, const float* rvw, const float* rsw,
                              const float* rsb, const float* rsa, const float* rta,
                              float* params, double* sums) {
    if (threadIdx.x == 0) {
        float ls = softplusf(rls[0]);
        float vw = softplusf(rvw[0]);
        float sw = softplusf(rsw[0]);
        float sb = softplusf(rsb[0]);
        float a0 = softplusf(rsa[0]) * softplusf(rta[0]);
        float a1 = softplusf(rsa[1]) * softplusf(rta[1]);
        float vw2 = vw * vw, sw2 = sw * sw, sb2 = sb * sb;
        params[0] = 1.f / ls;
        params[1] = vw2 * sb2 * (a0 + a1);  // c_add
        params[2] = vw2 * sw2 * a0;         // w0
        params[3] = vw2 * sw2 * a1;         // w1
        sums[0] = 0.0; sums[1] = 0.0; sums[2] = 0.0;
    }
}

// ---------------- squared norms of feat/ls ----------------
__global__ void sqnorm_kernel(const float* feat, const float* params, float* xn) {
    int r = blockIdx.x;
    int l = threadIdx.x;  // 64 lanes
    float inv_ls = params[0];
    float v0 = feat[r * DD + l] * inv_ls;
    float v1 = feat[r * DD + 64 + l] * inv_ls;
    float s = v0 * v0 + v1 * v1;
    for (int off = 32; off; off >>= 1) s += __shfl_xor(s, off);
    if (l == 0) xn[r] = s;
}

// ---------------- C0 = exp(-0.5 * sqdist) , fp32 tiled matmul ----------------
__global__ __launch_bounds__(256) void c0_kernel(const float* feat, const float* params,
                                                 const float* xn, float* C0) {
    __shared__ float As[32][DD + 1];
    __shared__ float Bs[32][DD + 1];
    float inv_ls = params[0];
    int r0 = blockIdx.y * 32, c0 = blockIdx.x * 32;
    int t = threadIdx.x + threadIdx.y * 16;
    for (int i = t; i < 32 * DD / 4; i += 256) {
        int row = (i * 4) / DD;
        int col = (i * 4) % DD;
        float4 a = *(const float4*)&feat[(size_t)(r0 + row) * DD + col];
        As[row][col + 0] = a.x * inv_ls;
        As[row][col + 1] = a.y * inv_ls;
        As[row][col + 2] = a.z * inv_ls;
        As[row][col + 3] = a.w * inv_ls;
        float4 b = *(const float4*)&feat[(size_t)(c0 + row) * DD + col];
        Bs[row][col + 0] = b.x * inv_ls;
        Bs[row][col + 1] = b.y * inv_ls;
        Bs[row][col + 2] = b.z * inv_ls;
        Bs[row][col + 3] = b.w * inv_ls;
    }
    __syncthreads();
    int tx = threadIdx.x, ty = threadIdx.y;
    float acc00 = 0.f, acc01 = 0.f, acc10 = 0.f, acc11 = 0.f;
    for (int k = 0; k < DD; k++) {
        float a0 = As[ty * 2 + 0][k], a1 = As[ty * 2 + 1][k];
        float b0 = Bs[tx * 2 + 0][k], b1 = Bs[tx * 2 + 1][k];
        acc00 += a0 * b0; acc01 += a0 * b1;
        acc10 += a1 * b0; acc11 += a1 * b1;
    }
    float accs[2][2] = {{acc00, acc01}, {acc10, acc11}};
    for (int i = 0; i < 2; i++)
        for (int j = 0; j < 2; j++) {
            int r = r0 + ty * 2 + i, c = c0 + tx * 2 + j;
            float sq = xn[r] + xn[c] - 2.f * accs[i][j];
            sq = fmaxf(sq, 0.f);
            C0[(size_t)r * NN + c] = expf(-0.5f * sq);
        }
}

// ---------------- CSR extraction (block-masked), deterministic ----------------
// Writes: nnzc (capped 64), colsa (absolute cols, int[64]),
//         pcols (relative cols, u16[8], padded with 2048 = zero slot)
__global__ void extract_kernel(const float* adj, int* nnzc, int* colsa, ushort* pcols) {
    __shared__ int sc[MAXNNZ];
    int b = blockIdx.x;        // i*NN + r
    int i = b >> 12;
    int r = b & (NN - 1);
    int lane = threadIdx.x;    // 64
    int base = (r < SS) ? 0 : SS;
    const float* arow = adj + ((size_t)i * NN + r) * NN + base;
    int cnt = 0;
    for (int it = 0; it < SS / 64; ++it) {
        int c = it * 64 + lane;
        float v = arow[c];
        unsigned long long m = __ballot(v != 0.f);
        if (v != 0.f) {
            int pos = cnt + __popcll(m & ((1ull << lane) - 1ull));
            if (pos < MAXNNZ) sc[pos] = c;  // relative col
        }
        cnt += __popcll(m);
    }
    if (cnt > MAXNNZ) cnt = MAXNNZ;
    __syncthreads();
    if (lane < cnt) colsa[(size_t)b * MAXNNZ + lane] = base + sc[lane];
    if (lane < 8) {
        int mn = cnt < 8 ? cnt : 8;
        pcols[(size_t)b * 8 + lane] = (ushort)(lane < mn ? sc[lane] : SS);
    }
    if (lane == 0) nnzc[b] = cnt;
}

// ---------------- passA: U_i = K * A_i^T (rows streamed through LDS) ----------------
// U_i[j, c] = sum_{k in nbr_i(c)} K[j, k]   (valid because K is symmetric)
__global__ __launch_bounds__(256) void passA_kernel(const float* K, const int* nnzc,
                                                    const int* colsa, const ushort* pcols,
                                                    float* U0, float* U1) {
    __shared__ uint4 sidx[2][CB];          // 8 u16 rel indices per col
    __shared__ ushort scnt[2][CB];
    __shared__ float rowbuf[2][SS + 8];    // double-buffered half-row + zero slot at [SS]
    int t = threadIdx.x;
    int cb = blockIdx.x;                   // 0..3
    int c0 = cb * CB;
    int kbase = (c0 >= SS) ? SS : 0;
    int j0 = blockIdx.y * JG;

    for (int a = 0; a < 2; a++)
        for (int q = 0; q < 4; q++) {
            int cw = t + 256 * q;
            sidx[a][cw] = ((const uint4*)pcols)[(size_t)a * NN + c0 + cw];
            scnt[a][cw] = (ushort)nnzc[a * NN + c0 + cw];
        }
    if (t < 8) { rowbuf[0][SS + t] = 0.f; rowbuf[1][SS + t] = 0.f; }

    // prefetch first row into regs
    const float4* src = (const float4*)(K + (size_t)j0 * NN + kbase);
    float4 va = src[t], vb = src[t + 256];
    __syncthreads();

    for (int jj = 0; jj < JG; ++jj) {
        int cur = jj & 1;
        float4* rb4 = (float4*)&rowbuf[cur][0];
        rb4[t] = va;
        rb4[t + 256] = vb;
        if (jj + 1 < JG) {
            const float4* nsrc = (const float4*)(K + (size_t)(j0 + jj + 1) * NN + kbase);
            va = nsrc[t];
            vb = nsrc[t + 256];
        }
        __syncthreads();
        const float* rb = &rowbuf[cur][0];
        size_t j = (size_t)(j0 + jj);
        for (int a = 0; a < 2; a++) {
            float* Ua = a ? U1 : U0;
            for (int q = 0; q < 4; q++) {
                int cw = t + 256 * q;
                uint4 L = sidx[a][cw];
                float acc = rb[L.x & 0xffff] + rb[L.x >> 16]
                          + rb[L.y & 0xffff] + rb[L.y >> 16]
                          + rb[L.z & 0xffff] + rb[L.z >> 16]
                          + rb[L.w & 0xffff] + rb[L.w >> 16];
                int cnt = scnt[a][cw];
                if (cnt > 8) {
                    const int* crow = colsa + ((size_t)a * NN + c0 + cw) * MAXNNZ;
                    for (int k = 8; k < cnt; k++) acc += rb[crow[k] - kbase];
                }
                Ua[j * NN + c0 + cw] = acc;
            }
        }
        // one barrier per iter is safe: next write targets the other buffer
        __syncthreads();
    }
}

// ---------------- diag of layer-1 K -> svec ----------------
__global__ void diagk_kernel(const float* U0, const float* U1, const int* nnzc,
                             const int* colsa, const float* params, float* svec) {
    int r = blockIdx.x * 256 + threadIdx.x;
    if (r >= NN) return;
    float c_add = params[1], w0 = params[2], w1 = params[3];
    float a = 0.f, b = 0.f;
    {
        int cnt = nnzc[r];
        const int* crow = colsa + (size_t)r * MAXNNZ;
        for (int k = 0; k < cnt; k++) a += U0[(size_t)crow[k] * NN + r];
    }
    {
        int cnt = nnzc[NN + r];
        const int* crow = colsa + (size_t)(NN + r) * MAXNNZ;
        for (int k = 0; k < cnt; k++) b += U1[(size_t)crow[k] * NN + r];
    }
    float d = c_add + w0 * a + w1 * b;
    svec[r] = sqrtf(fmaxf(d, 0.f)) + 1e-5f;
}

// ---------------- passB: out[r,c] = c_add + w0*sum U0[nbr0(r),c] + w1*sum U1[nbr1(r),c]
// MODE 0: apply relu_cov transform (layer 1).  MODE 1: plain + block-sum atomics (layer 2).
template <int MODE>
__global__ __launch_bounds__(256) void passB_kernel(const float* U0, const float* U1,
                                                    const int* nnzc, const int* colsa,
                                                    const float* params, const float* svec,
                                                    float* Kout, double* sums) {
    __shared__ double red[256];
    int r = blockIdx.y;
    int cb = blockIdx.x;
    int c = cb * 1024 + threadIdx.x * 4;
    float c_add = params[1], w0 = params[2], w1 = params[3];
    float ax = 0.f, ay = 0.f, az = 0.f, aw = 0.f;
    float bx = 0.f, by = 0.f, bz = 0.f, bw = 0.f;
    {
        int cnt = nnzc[r];
        const int* crow = colsa + (size_t)r * MAXNNZ;
        int k = 0;
        for (; k + 4 <= cnt; k += 4) {
            int4 ci = *(const int4*)&crow[k];
            int j0 = __builtin_amdgcn_readfirstlane(ci.x);
            int j1 = __builtin_amdgcn_readfirstlane(ci.y);
            int j2 = __builtin_amdgcn_readfirstlane(ci.z);
            int j3 = __builtin_amdgcn_readfirstlane(ci.w);
            float4 v0 = *(const float4*)&U0[(size_t)j0 * NN + c];
            float4 v1 = *(const float4*)&U0[(size_t)j1 * NN + c];
            float4 v2 = *(const float4*)&U0[(size_t)j2 * NN + c];
            float4 v3 = *(const float4*)&U0[(size_t)j3 * NN + c];
            ax += v0.x + v1.x + v2.x + v3.x;
            ay += v0.y + v1.y + v2.y + v3.y;
            az += v0.z + v1.z + v2.z + v3.z;
            aw += v0.w + v1.w + v2.w + v3.w;
        }
        for (; k < cnt; k++) {
            int j = __builtin_amdgcn_readfirstlane(crow[k]);
            float4 v = *(const float4*)&U0[(size_t)j * NN + c];
            ax += v.x; ay += v.y; az += v.z; aw += v.w;
        }
    }
    {
        int cnt = nnzc[NN + r];
        const int* crow = colsa + (size_t)(NN + r) * MAXNNZ;
        int k = 0;
        for (; k + 4 <= cnt; k += 4) {
            int4 ci = *(const int4*)&crow[k];
            int j0 = __builtin_amdgcn_readfirstlane(ci.x);
            int j1 = __builtin_amdgcn_readfirstlane(ci.y);
            int j2 = __builtin_amdgcn_readfirstlane(ci.z);
            int j3 = __builtin_amdgcn_readfirstlane(ci.w);
            float4 v0 = *(const float4*)&U1[(size_t)j0 * NN + c];
            float4 v1 = *(const float4*)&U1[(size_t)j1 * NN + c];
            float4 v2 = *(const float4*)&U1[(size_t)j2 * NN + c];
            float4 v3 = *(const float4*)&U1[(size_t)j3 * NN + c];
            bx += v0.x + v1.x + v2.x + v3.x;
            by += v0.y + v1.y + v2.y + v3.y;
            bz += v0.z + v1.z + v2.z + v3.z;
            bw += v0.w + v1.w + v2.w + v3.w;
        }
        for (; k < cnt; k++) {
            int j = __builtin_amdgcn_readfirstlane(crow[k]);
            float4 v = *(const float4*)&U1[(size_t)j * NN + c];
            bx += v.x; by += v.y; bz += v.z; bw += v.w;
        }
    }
    float kv[4];
    kv[0] = c_add + w0 * ax + w1 * bx;
    kv[1] = c_add + w0 * ay + w1 * by;
    kv[2] = c_add + w0 * az + w1 * bz;
    kv[3] = c_add + w0 * aw + w1 * bw;

    if (MODE == 0) {
        const float PIF = 3.14159265358979323846f;
        const float INV2PI = 0.15915494309189535f;
        float sr = svec[r];
        float4 sc4 = *(const float4*)&svec[c];
        float scs[4] = {sc4.x, sc4.y, sc4.z, sc4.w};
        for (int q = 0; q < 4; q++) {
            float p = sr * scs[q];
            float cc = kv[q] / p;
            cc = fminf(fmaxf(cc, -1.f + 1e-6f), 1.f - 1e-6f);
            float th = acosf(cc);
            float sth = sqrtf(fmaxf(1.f - cc * cc, 0.f));
            kv[q] = INV2PI * (sth + (PIF - th) * cc) * p;
        }
    }
    float4 o = {kv[0], kv[1], kv[2], kv[3]};
    *(float4*)&Kout[(size_t)r * NN + c] = o;

    if (MODE == 1) {
        int t = threadIdx.x;
        red[t] = (double)kv[0] + (double)kv[1] + (double)kv[2] + (double)kv[3];
        __syncthreads();
        for (int off = 128; off; off >>= 1) {
            if (t < off) red[t] += red[t + off];
            __syncthreads();
        }
        if (t == 0) {
            bool rs = r < SS;
            bool ch = cb >= 2;  // col half
            if (rs && !ch) atomicAdd(&sums[0], red[0]);
            else if (rs && ch) atomicAdd(&sums[1], red[0]);
            else if (!rs && ch) atomicAdd(&sums[2], red[0]);
        }
    }
}

// ---------------- final: gather + index_K scale ----------------
__global__ __launch_bounds__(256) void final_kernel(const float* K, const int* x1, const int* x2,
                                                    const double* sums, float* out) {
    size_t idx = (size_t)blockIdx.x * 256 + threadIdx.x;  // quad index
    int i = (int)(idx >> 10);
    int j4 = (int)(idx & 1023) << 2;
    const double invc = 1.0 / ((double)SS * (double)SS);
    float mss = (float)(sums[0] * invc);
    float mst = (float)(sums[1] * invc);
    float mtt = (float)(sums[2] * invc);
    int row = x1[i];
    float o[4];
    for (int j = 0; j < 4; j++) {
        int col = x2[j4 + j];
        float v = K[(size_t)row * NN + col];
        float m = (row < SS) ? (col < SS ? mss : mst) : (col < SS ? mst : mtt);
        o[j] = v * m;
    }
    float4 ov = {o[0], o[1], o[2], o[3]};
    *(float4*)&out[(size_t)i * NN + j4] = ov;
}

extern "C" void kernel_launch(void* const* d_in, const int* in_sizes, int n_in,
                              void* d_out, int out_size, void* d_ws, size_t ws_size,
                              hipStream_t stream) {
    const float* feat = (const float*)d_in[0];
    const float* adj  = (const float*)d_in[1];
    const float* rls  = (const float*)d_in[2];
    const float* rvw  = (const float*)d_in[3];
    const float* rsw  = (const float*)d_in[4];
    const float* rsb  = (const float*)d_in[5];
    const float* rsa  = (const float*)d_in[6];
    const float* rta  = (const float*)d_in[7];
    const int*   x1   = (const int*)d_in[8];
    const int*   x2   = (const int*)d_in[9];
    float* out = (float*)d_out;

    const size_t PNN = (size_t)NN * NN;
    char* w = (char*)d_ws;
    float*  params = (float*)(w + 0);            // 16 floats
    double* sums   = (double*)(w + 64);          // 3 doubles
    float*  xn     = (float*)(w + 128);          // 16 KB
    float*  svec   = (float*)(w + 128 + 16384);  // 16 KB
    int*    nnzc   = (int*)(w + 128 + 32768);    // 32 KB
    int*    colsa  = (int*)(w + 128 + 65536);    // 2 MiB
    ushort* pcols  = (ushort*)(w + 128 + 65536 + (size_t)NADJ * NN * MAXNNZ * 4);  // 128 KB
    size_t  big0   = ((size_t)(128 + 65536) + (size_t)NADJ * NN * MAXNNZ * 4
                      + (size_t)NADJ * NN * 8 * 2 + 255) & ~(size_t)255;
    float* bufK = (float*)(w + big0);
    float* U0   = bufK + PNN;
    float* U1   = (ws_size >= big0 + 3 * PNN * 4) ? (U0 + PNN) : (float*)d_out;

    params_kernel<<<1, 64, 0, stream>>>(rls, rvw, rsw, rsb, rsa, rta, params, sums);
    sqnorm_kernel<<<NN, 64, 0, stream>>>(feat, params, xn);
    c0_kernel<<<dim3(NN / 32, NN / 32), dim3(16, 16), 0, stream>>>(feat, params, xn, bufK);
    extract_kernel<<<NADJ * NN, 64, 0, stream>>>(adj, nnzc, colsa, pcols);

    // layer 1
    passA_kernel<<<dim3(4, NN / JG), 256, 0, stream>>>(bufK, nnzc, colsa, pcols, U0, U1);
    diagk_kernel<<<16, 256, 0, stream>>>(U0, U1, nnzc, colsa, params, svec);
    passB_kernel<0><<<dim3(4, NN), 256, 0, stream>>>(U0, U1, nnzc, colsa, params, svec, bufK, sums);

    // layer 2
    passA_kernel<<<dim3(4, NN / JG), 256, 0, stream>>>(bufK, nnzc, colsa, pcols, U0, U1);
    passB_kernel<1><<<dim3(4, NN), 256, 0, stream>>>(U0, U1, nnzc, colsa, params, svec, bufK, sums);

    // final scale/gather
    final_kernel<<<16384, 256, 0, stream>>>(bufK, x1, x2, sums, out);
}

// Round 3
// 626.993 us; speedup vs baseline: 1.3144x; 1.1950x over previous
//
#include <hip/hip_runtime.h>
#include <math.h>

#define NN 4096
#define SS 2048
#define DD 128
#define NADJ 2
#define MAXNNZ 64
#define CB 1024   // cols per passA block
#define JG 32     // rows per passA block

typedef short v8s __attribute__((ext_vector_type(8)));
typedef float v4f __attribute__((ext_vector_type(4)));

__device__ __forceinline__ float softplusf(float x) {
    if (x > 20.f) return x;
    if (x < -20.f) return expf(x);
    return log1pf(expf(x));
}

__device__ __forceinline__ ushort f2bf(float f) {
    unsigned int u = __float_as_uint(f);
    unsigned int r = (u + 0x7fff + ((u >> 16) & 1)) >> 16;  // RNE
    return (ushort)r;
}
__device__ __forceinline__ float bf2f(ushort h) {
    return __uint_as_float(((unsigned int)h) << 16);
}

// ---------------- params + zero sums ----------------
__global__ void params_kernel(const float* rls, const float* rvw, const float* rsw,
                              const float* rsb, const float* rsa, const float* rta,
                              float* params, double* sums) {
    if (threadIdx.x == 0) {
        float ls = softplusf(rls[0]);
        float vw = softplusf(rvw[0]);
        float sw = softplusf(rsw[0]);
        float sb = softplusf(rsb[0]);
        float a0 = softplusf(rsa[0]) * softplusf(rta[0]);
        float a1 = softplusf(rsa[1]) * softplusf(rta[1]);
        float vw2 = vw * vw, sw2 = sw * sw, sb2 = sb * sb;
        params[0] = 1.f / ls;
        params[1] = vw2 * sb2 * (a0 + a1);  // c_add
        params[2] = vw2 * sw2 * a0;         // w0
        params[3] = vw2 * sw2 * a1;         // w1
        sums[0] = 0.0; sums[1] = 0.0; sums[2] = 0.0;
    }
}

// ---------------- xb = bf16(feat/ls), xn = ||xb_row||^2 ----------------
__global__ void xb_kernel(const float* feat, const float* params, ushort* xb, float* xn) {
    int r = blockIdx.x;
    int l = threadIdx.x;  // 64 lanes
    float inv_ls = params[0];
    ushort h0 = f2bf(feat[r * DD + l] * inv_ls);
    ushort h1 = f2bf(feat[r * DD + 64 + l] * inv_ls);
    xb[r * DD + l] = h0;
    xb[r * DD + 64 + l] = h1;
    float v0 = bf2f(h0), v1 = bf2f(h1);
    float s = v0 * v0 + v1 * v1;
    for (int off = 32; off; off >>= 1) s += __shfl_xor(s, off);
    if (l == 0) xn[r] = s;
}

// ---------------- C0 = exp(-0.5 * sqdist) via bf16 MFMA ----------------
__global__ __launch_bounds__(256) void c0_mfma_kernel(const ushort* xb, const float* xn,
                                                      float* C0) {
    __shared__ float xr[128], xc[128];
    int t = threadIdx.x;
    int r0 = blockIdx.y * 128, c0 = blockIdx.x * 128;
    if (t < 128) xr[t] = xn[r0 + t];
    else xc[t - 128] = xn[c0 + (t - 128)];
    __syncthreads();

    int w = t >> 6, l = t & 63;
    int wr = w >> 1, wc = w & 1;
    int lr = l & 15;          // fragment row/col within 16
    int lk = (l >> 4) * 8;    // k-chunk base
    const ushort* pa = xb + (size_t)(r0 + wr * 64 + lr) * DD + lk;
    const ushort* pb = xb + (size_t)(c0 + wc * 64 + lr) * DD + lk;

    v4f acc[4][4] = {};
    for (int ks = 0; ks < 4; ks++) {
        v8s a[4], b[4];
        for (int m = 0; m < 4; m++) a[m] = *(const v8s*)(pa + (size_t)m * 16 * DD + ks * 32);
        for (int n = 0; n < 4; n++) b[n] = *(const v8s*)(pb + (size_t)n * 16 * DD + ks * 32);
        for (int m = 0; m < 4; m++)
            for (int n = 0; n < 4; n++)
                acc[m][n] = __builtin_amdgcn_mfma_f32_16x16x32_bf16(a[m], b[n], acc[m][n], 0, 0, 0);
    }

    int rbase = wr * 64;  // relative to r0
    int cbase = wc * 64;
    for (int m = 0; m < 4; m++) {
        for (int n = 0; n < 4; n++) {
            int ocol = cbase + n * 16 + lr;
            float xnc = xc[ocol];
            for (int j = 0; j < 4; j++) {
                int orow = rbase + m * 16 + (l >> 4) * 4 + j;
                float sq = xr[orow] + xnc - 2.f * acc[m][n][j];
                sq = fmaxf(sq, 0.f);
                C0[(size_t)(r0 + orow) * NN + c0 + ocol] = expf(-0.5f * sq);
            }
        }
    }
}

// ---------------- CSR extraction (block-masked), deterministic ----------------
__global__ void extract_kernel(const float* adj, int* nnzc, int* colsa, ushort* pcols) {
    __shared__ int sc[MAXNNZ];
    int b = blockIdx.x;        // i*NN + r
    int i = b >> 12;
    int r = b & (NN - 1);
    int lane = threadIdx.x;    // 64
    int base = (r < SS) ? 0 : SS;
    const float* arow = adj + ((size_t)i * NN + r) * NN + base;
    int cnt = 0;
    for (int it = 0; it < SS / 64; ++it) {
        int c = it * 64 + lane;
        float v = arow[c];
        unsigned long long m = __ballot(v != 0.f);
        if (v != 0.f) {
            int pos = cnt + __popcll(m & ((1ull << lane) - 1ull));
            if (pos < MAXNNZ) sc[pos] = c;  // relative col
        }
        cnt += __popcll(m);
    }
    if (cnt > MAXNNZ) cnt = MAXNNZ;
    __syncthreads();
    if (lane < cnt) colsa[(size_t)b * MAXNNZ + lane] = base + sc[lane];
    if (lane < 8) {
        int mn = cnt < 8 ? cnt : 8;
        pcols[(size_t)b * 8 + lane] = (ushort)(lane < mn ? sc[lane] : SS);
    }
    if (lane == 0) nnzc[b] = cnt;
}

// ---------------- passA: U_i[j,c] = sum_{k in nbr_i(c)} K[j,k] (K symmetric) ----------------
__global__ __launch_bounds__(256) void passA_kernel(const float* K, const int* nnzc,
                                                    const int* colsa, const ushort* pcols,
                                                    float* U0, float* U1) {
    __shared__ uint4 sidx[2][CB];          // 8 u16 rel indices per col
    __shared__ ushort scnt[2][CB];
    __shared__ float rowbuf[2][SS + 8];    // double-buffered half-row + zero slot at [SS]
    int t = threadIdx.x;
    int cb = blockIdx.x;                   // 0..3
    int c0 = cb * CB;
    int kbase = (c0 >= SS) ? SS : 0;
    int j0 = blockIdx.y * JG;

    for (int a = 0; a < 2; a++)
        for (int q = 0; q < 4; q++) {
            int cw = t + 256 * q;
            sidx[a][cw] = ((const uint4*)pcols)[(size_t)a * NN + c0 + cw];
            scnt[a][cw] = (ushort)nnzc[a * NN + c0 + cw];
        }
    if (t < 8) { rowbuf[0][SS + t] = 0.f; rowbuf[1][SS + t] = 0.f; }

    const float4* src = (const float4*)(K + (size_t)j0 * NN + kbase);
    float4 va = src[t], vb = src[t + 256];
    __syncthreads();

    for (int jj = 0; jj < JG; ++jj) {
        int cur = jj & 1;
        float4* rb4 = (float4*)&rowbuf[cur][0];
        rb4[t] = va;
        rb4[t + 256] = vb;
        if (jj + 1 < JG) {
            const float4* nsrc = (const float4*)(K + (size_t)(j0 + jj + 1) * NN + kbase);
            va = nsrc[t];
            vb = nsrc[t + 256];
        }
        __syncthreads();
        const float* rb = &rowbuf[cur][0];
        size_t j = (size_t)(j0 + jj);
        for (int a = 0; a < 2; a++) {
            float* Ua = a ? U1 : U0;
            for (int q = 0; q < 4; q++) {
                int cw = t + 256 * q;
                uint4 L = sidx[a][cw];
                float acc = rb[L.x & 0xffff] + rb[L.x >> 16]
                          + rb[L.y & 0xffff] + rb[L.y >> 16]
                          + rb[L.z & 0xffff] + rb[L.z >> 16]
                          + rb[L.w & 0xffff] + rb[L.w >> 16];
                int cnt = scnt[a][cw];
                if (cnt > 8) {
                    const int* crow = colsa + ((size_t)a * NN + c0 + cw) * MAXNNZ;
                    for (int k = 8; k < cnt; k++) acc += rb[crow[k] - kbase];
                }
                Ua[j * NN + c0 + cw] = acc;
            }
        }
        __syncthreads();
    }
}

// ---------------- diag of layer-1 K -> svec ----------------
__global__ void diagk_kernel(const float* U0, const float* U1, const int* nnzc,
                             const int* colsa, const float* params, float* svec) {
    int r = blockIdx.x * 256 + threadIdx.x;
    if (r >= NN) return;
    float c_add = params[1], w0 = params[2], w1 = params[3];
    float a = 0.f, b = 0.f;
    {
        int cnt = nnzc[r];
        const int* crow = colsa + (size_t)r * MAXNNZ;
        for (int k = 0; k < cnt; k++) a += U0[(size_t)crow[k] * NN + r];
    }
    {
        int cnt = nnzc[NN + r];
        const int* crow = colsa + (size_t)(NN + r) * MAXNNZ;
        for (int k = 0; k < cnt; k++) b += U1[(size_t)crow[k] * NN + r];
    }
    float d = c_add + w0 * a + w1 * b;
    svec[r] = sqrtf(fmaxf(d, 0.f)) + 1e-5f;
}

// ---------------- passB ----------------
template <int MODE>
__global__ __launch_bounds__(256) void passB_kernel(const float* U0, const float* U1,
                                                    const int* nnzc, const int* colsa,
                                                    const float* params, const float* svec,
                                                    float* Kout, double* sums) {
    __shared__ double red[256];
    int r = blockIdx.y;
    int cb = blockIdx.x;
    int c = cb * 1024 + threadIdx.x * 4;
    float c_add = params[1], w0 = params[2], w1 = params[3];
    float ax = 0.f, ay = 0.f, az = 0.f, aw = 0.f;
    float bx = 0.f, by = 0.f, bz = 0.f, bw = 0.f;
    {
        int cnt = nnzc[r];
        const int* crow = colsa + (size_t)r * MAXNNZ;
        int k = 0;
        for (; k + 4 <= cnt; k += 4) {
            int4 ci = *(const int4*)&crow[k];
            int j0 = __builtin_amdgcn_readfirstlane(ci.x);
            int j1 = __builtin_amdgcn_readfirstlane(ci.y);
            int j2 = __builtin_amdgcn_readfirstlane(ci.z);
            int j3 = __builtin_amdgcn_readfirstlane(ci.w);
            float4 v0 = *(const float4*)&U0[(size_t)j0 * NN + c];
            float4 v1 = *(const float4*)&U0[(size_t)j1 * NN + c];
            float4 v2 = *(const float4*)&U0[(size_t)j2 * NN + c];
            float4 v3 = *(const float4*)&U0[(size_t)j3 * NN + c];
            ax += v0.x + v1.x + v2.x + v3.x;
            ay += v0.y + v1.y + v2.y + v3.y;
            az += v0.z + v1.z + v2.z + v3.z;
            aw += v0.w + v1.w + v2.w + v3.w;
        }
        for (; k < cnt; k++) {
            int j = __builtin_amdgcn_readfirstlane(crow[k]);
            float4 v = *(const float4*)&U0[(size_t)j * NN + c];
            ax += v.x; ay += v.y; az += v.z; aw += v.w;
        }
    }
    {
        int cnt = nnzc[NN + r];
        const int* crow = colsa + (size_t)(NN + r) * MAXNNZ;
        int k = 0;
        for (; k + 4 <= cnt; k += 4) {
            int4 ci = *(const int4*)&crow[k];
            int j0 = __builtin_amdgcn_readfirstlane(ci.x);
            int j1 = __builtin_amdgcn_readfirstlane(ci.y);
            int j2 = __builtin_amdgcn_readfirstlane(ci.z);
            int j3 = __builtin_amdgcn_readfirstlane(ci.w);
            float4 v0 = *(const float4*)&U1[(size_t)j0 * NN + c];
            float4 v1 = *(const float4*)&U1[(size_t)j1 * NN + c];
            float4 v2 = *(const float4*)&U1[(size_t)j2 * NN + c];
            float4 v3 = *(const float4*)&U1[(size_t)j3 * NN + c];
            bx += v0.x + v1.x + v2.x + v3.x;
            by += v0.y + v1.y + v2.y + v3.y;
            bz += v0.z + v1.z + v2.z + v3.z;
            bw += v0.w + v1.w + v2.w + v3.w;
        }
        for (; k < cnt; k++) {
            int j = __builtin_amdgcn_readfirstlane(crow[k]);
            float4 v = *(const float4*)&U1[(size_t)j * NN + c];
            bx += v.x; by += v.y; bz += v.z; bw += v.w;
        }
    }
    float kv[4];
    kv[0] = c_add + w0 * ax + w1 * bx;
    kv[1] = c_add + w0 * ay + w1 * by;
    kv[2] = c_add + w0 * az + w1 * bz;
    kv[3] = c_add + w0 * aw + w1 * bw;

    if (MODE == 0) {
        const float PIF = 3.14159265358979323846f;
        const float INV2PI = 0.15915494309189535f;
        float sr = svec[r];
        float4 sc4 = *(const float4*)&svec[c];
        float scs[4] = {sc4.x, sc4.y, sc4.z, sc4.w};
        for (int q = 0; q < 4; q++) {
            float p = sr * scs[q];
            float cc = kv[q] / p;
            cc = fminf(fmaxf(cc, -1.f + 1e-6f), 1.f - 1e-6f);
            float th = acosf(cc);
            float sth = sqrtf(fmaxf(1.f - cc * cc, 0.f));
            kv[q] = INV2PI * (sth + (PIF - th) * cc) * p;
        }
    }
    float4 o = {kv[0], kv[1], kv[2], kv[3]};
    *(float4*)&Kout[(size_t)r * NN + c] = o;

    if (MODE == 1) {
        int t = threadIdx.x;
        red[t] = (double)kv[0] + (double)kv[1] + (double)kv[2] + (double)kv[3];
        __syncthreads();
        for (int off = 128; off; off >>= 1) {
            if (t < off) red[t] += red[t + off];
            __syncthreads();
        }
        if (t == 0) {
            bool rs = r < SS;
            bool ch = cb >= 2;
            if (rs && !ch) atomicAdd(&sums[0], red[0]);
            else if (rs && ch) atomicAdd(&sums[1], red[0]);
            else if (!rs && ch) atomicAdd(&sums[2], red[0]);
        }
    }
}

// ---------------- final: gather + index_K scale ----------------
__global__ __launch_bounds__(256) void final_kernel(const float* K, const int* x1, const int* x2,
                                                    const double* sums, float* out) {
    size_t idx = (size_t)blockIdx.x * 256 + threadIdx.x;  // quad index
    int i = (int)(idx >> 10);
    int j4 = (int)(idx & 1023) << 2;
    const double invc = 1.0 / ((double)SS * (double)SS);
    float mss = (float)(sums[0] * invc);
    float mst = (float)(sums[1] * invc);
    float mtt = (float)(sums[2] * invc);
    int row = x1[i];
    float o[4];
    for (int j = 0; j < 4; j++) {
        int col = x2[j4 + j];
        float v = K[(size_t)row * NN + col];
        float m = (row < SS) ? (col < SS ? mss : mst) : (col < SS ? mst : mtt);
        o[j] = v * m;
    }
    float4 ov = {o[0], o[1], o[2], o[3]};
    *(float4*)&out[(size_t)i * NN + j4] = ov;
}

extern "C" void kernel_launch(void* const* d_in, const int* in_sizes, int n_in,
                              void* d_out, int out_size, void* d_ws, size_t ws_size,
                              hipStream_t stream) {
    const float* feat = (const float*)d_in[0];
    const float* adj  = (const float*)d_in[1];
    const float* rls  = (const float*)d_in[2];
    const float* rvw  = (const float*)d_in[3];
    const float* rsw  = (const float*)d_in[4];
    const float* rsb  = (const float*)d_in[5];
    const float* rsa  = (const float*)d_in[6];
    const float* rta  = (const float*)d_in[7];
    const int*   x1   = (const int*)d_in[8];
    const int*   x2   = (const int*)d_in[9];
    float* out = (float*)d_out;

    const size_t PNN = (size_t)NN * NN;
    char* w = (char*)d_ws;
    float*  params = (float*)(w + 0);            // 16 floats
    double* sums   = (double*)(w + 64);          // 3 doubles
    float*  xn     = (float*)(w + 128);          // 16 KB
    float*  svec   = (float*)(w + 128 + 16384);  // 16 KB
    int*    nnzc   = (int*)(w + 128 + 32768);    // 32 KB
    int*    colsa  = (int*)(w + 128 + 65536);    // 2 MiB
    ushort* pcols  = (ushort*)(w + 128 + 65536 + (size_t)NADJ * NN * MAXNNZ * 4);  // 128 KB
    ushort* xb     = (ushort*)(w + 128 + 65536 + (size_t)NADJ * NN * MAXNNZ * 4
                               + (size_t)NADJ * NN * 8 * 2);                        // 1 MiB
    size_t  big0   = ((size_t)(128 + 65536) + (size_t)NADJ * NN * MAXNNZ * 4
                      + (size_t)NADJ * NN * 8 * 2 + (size_t)NN * DD * 2 + 255) & ~(size_t)255;
    float* bufK = (float*)(w + big0);
    float* U0   = bufK + PNN;
    float* U1   = (ws_size >= big0 + 3 * PNN * 4) ? (U0 + PNN) : (float*)d_out;

    params_kernel<<<1, 64, 0, stream>>>(rls, rvw, rsw, rsb, rsa, rta, params, sums);
    xb_kernel<<<NN, 64, 0, stream>>>(feat, params, xb, xn);
    c0_mfma_kernel<<<dim3(NN / 128, NN / 128), 256, 0, stream>>>(xb, xn, bufK);
    extract_kernel<<<NADJ * NN, 64, 0, stream>>>(adj, nnzc, colsa, pcols);

    // layer 1
    passA_kernel<<<dim3(4, NN / JG), 256, 0, stream>>>(bufK, nnzc, colsa, pcols, U0, U1);
    diagk_kernel<<<16, 256, 0, stream>>>(U0, U1, nnzc, colsa, params, svec);
    passB_kernel<0><<<dim3(4, NN), 256, 0, stream>>>(U0, U1, nnzc, colsa, params, svec, bufK, sums);

    // layer 2
    passA_kernel<<<dim3(4, NN / JG), 256, 0, stream>>>(bufK, nnzc, colsa, pcols, U0, U1);
    passB_kernel<1><<<dim3(4, NN), 256, 0, stream>>>(U0, U1, nnzc, colsa, params, svec, bufK, sums);

    // final scale/gather
    final_kernel<<<16384, 256, 0, stream>>>(bufK, x1, x2, sums, out);
}

// Round 4
// 436.736 us; speedup vs baseline: 1.8870x; 1.4356x over previous
//
#include <hip/hip_runtime.h>
#include <math.h>

#define NN 4096
#define SS 2048
#define DD 128
#define NADJ 2
#define MAXNNZ 64

typedef short v8s __attribute__((ext_vector_type(8)));
typedef float v4f __attribute__((ext_vector_type(4)));

__device__ __forceinline__ float softplusf(float x) {
    if (x > 20.f) return x;
    if (x < -20.f) return expf(x);
    return log1pf(expf(x));
}

__device__ __forceinline__ ushort f2bf(float f) {
    unsigned int u = __float_as_uint(f);
    unsigned int r = (u + 0x7fff + ((u >> 16) & 1)) >> 16;  // RNE
    return (ushort)r;
}
__device__ __forceinline__ float bf2f(ushort h) {
    return __uint_as_float(((unsigned int)h) << 16);
}

// ---------------- params + zero sums ----------------
__global__ void params_kernel(const float* rls, const float* rvw, const float* rsw,
                              const float* rsb, const float* rsa, const float* rta,
                              float* params, double* sums) {
    if (threadIdx.x == 0) {
        float ls = softplusf(rls[0]);
        float vw = softplusf(rvw[0]);
        float sw = softplusf(rsw[0]);
        float sb = softplusf(rsb[0]);
        float a0 = softplusf(rsa[0]) * softplusf(rta[0]);
        float a1 = softplusf(rsa[1]) * softplusf(rta[1]);
        float vw2 = vw * vw, sw2 = sw * sw, sb2 = sb * sb;
        params[0] = 1.f / ls;
        params[1] = vw2 * sb2 * (a0 + a1);  // c_add
        params[2] = vw2 * sw2 * a0;         // w0
        params[3] = vw2 * sw2 * a1;         // w1
        sums[0] = 0.0; sums[1] = 0.0; sums[2] = 0.0;
    }
}

// ---------------- xb = bf16(feat/ls), xn = ||xb_row||^2 ----------------
__global__ void xb_kernel(const float* feat, const float* params, ushort* xb, float* xn) {
    int r = blockIdx.x;
    int l = threadIdx.x;  // 64 lanes
    float inv_ls = params[0];
    ushort h0 = f2bf(feat[r * DD + l] * inv_ls);
    ushort h1 = f2bf(feat[r * DD + 64 + l] * inv_ls);
    xb[r * DD + l] = h0;
    xb[r * DD + 64 + l] = h1;
    float v0 = bf2f(h0), v1 = bf2f(h1);
    float s = v0 * v0 + v1 * v1;
    for (int off = 32; off; off >>= 1) s += __shfl_xor(s, off);
    if (l == 0) xn[r] = s;
}

// ---------------- C0 = exp(-0.5 * sqdist) via bf16 MFMA ----------------
__global__ __launch_bounds__(256) void c0_mfma_kernel(const ushort* xb, const float* xn,
                                                      float* C0) {
    __shared__ float xr[128], xc[128];
    int t = threadIdx.x;
    int r0 = blockIdx.y * 128, c0 = blockIdx.x * 128;
    if (t < 128) xr[t] = xn[r0 + t];
    else xc[t - 128] = xn[c0 + (t - 128)];
    __syncthreads();

    int w = t >> 6, l = t & 63;
    int wr = w >> 1, wc = w & 1;
    int lr = l & 15;          // fragment row/col within 16
    int lk = (l >> 4) * 8;    // k-chunk base
    const ushort* pa = xb + (size_t)(r0 + wr * 64 + lr) * DD + lk;
    const ushort* pb = xb + (size_t)(c0 + wc * 64 + lr) * DD + lk;

    v4f acc[4][4] = {};
    for (int ks = 0; ks < 4; ks++) {
        v8s a[4], b[4];
        for (int m = 0; m < 4; m++) a[m] = *(const v8s*)(pa + (size_t)m * 16 * DD + ks * 32);
        for (int n = 0; n < 4; n++) b[n] = *(const v8s*)(pb + (size_t)n * 16 * DD + ks * 32);
        for (int m = 0; m < 4; m++)
            for (int n = 0; n < 4; n++)
                acc[m][n] = __builtin_amdgcn_mfma_f32_16x16x32_bf16(a[m], b[n], acc[m][n], 0, 0, 0);
    }

    int rbase = wr * 64;
    int cbase = wc * 64;
    for (int m = 0; m < 4; m++) {
        for (int n = 0; n < 4; n++) {
            int ocol = cbase + n * 16 + lr;
            float xnc = xc[ocol];
            for (int j = 0; j < 4; j++) {
                int orow = rbase + m * 16 + (l >> 4) * 4 + j;
                float sq = xr[orow] + xnc - 2.f * acc[m][n][j];
                sq = fmaxf(sq, 0.f);
                C0[(size_t)(r0 + orow) * NN + c0 + ocol] = expf(-0.5f * sq);
            }
        }
    }
}

// ---------------- CSR extraction (block-masked), deterministic ----------------
// colsa: absolute cols (int[64]); pcols: relative cols u16[8] with pad chosen so
// that base_c + pad == 4096 (the zero slot of the rowsum LDS array).
__global__ void extract_kernel(const float* adj, int* nnzc, int* colsa, ushort* pcols) {
    __shared__ int sc[MAXNNZ];
    int b = blockIdx.x;        // a*NN + r
    int i = b >> 12;
    int r = b & (NN - 1);
    int lane = threadIdx.x;    // 64
    int base = (r < SS) ? 0 : SS;
    const float* arow = adj + ((size_t)i * NN + r) * NN + base;
    int cnt = 0;
    for (int it = 0; it < SS / 64; ++it) {
        int c = it * 64 + lane;
        float v = arow[c];
        unsigned long long m = __ballot(v != 0.f);
        if (v != 0.f) {
            int pos = cnt + __popcll(m & ((1ull << lane) - 1ull));
            if (pos < MAXNNZ) sc[pos] = c;  // relative col
        }
        cnt += __popcll(m);
    }
    if (cnt > MAXNNZ) cnt = MAXNNZ;
    __syncthreads();
    if (lane < cnt) colsa[(size_t)b * MAXNNZ + lane] = base + sc[lane];
    if (lane < 8) {
        int mn = cnt < 8 ? cnt : 8;
        ushort pad = (ushort)(4096 - base);  // base 0 -> 4096 ; base 2048 -> 2048
        pcols[(size_t)b * 8 + lane] = (lane < mn) ? (ushort)sc[lane] : pad;
    }
    if (lane == 0) nnzc[b] = cnt;
}

// ---------------- diag of layer-1 K -> svec (double gather on C0) ----------------
__global__ void diag1_kernel(const float* C0, const int* nnzc, const int* colsa,
                             const float* params, float* svec) {
    int t = threadIdx.x;
    int r = blockIdx.x * 4 + (t >> 6);  // one wave per row
    int lane = t & 63;
    float c_add = params[1], w0 = params[2], w1 = params[3];
    float s = 0.f;
    for (int a = 0; a < 2; a++) {
        int b = a * NN + r;
        int cnt = nnzc[b];
        const int* crow = colsa + (size_t)b * MAXNNZ;
        int myk = crow[(lane < cnt) ? lane : 0];
        float wa = a ? w1 : w0;
        float acc = 0.f;
        for (int j = 0; j < cnt; j++) {
            int row = crow[j];
            if (lane < cnt) acc += C0[(size_t)row * NN + myk];
        }
        s += wa * acc;
    }
    for (int off = 32; off; off >>= 1) s += __shfl_xor(s, off);
    if (lane == 0) {
        float d = c_add + s;
        svec[r] = sqrtf(fmaxf(d, 0.f)) + 1e-5f;
    }
}

// ---------------- fused conv: one output row per block ----------------
// out[r,c] = c_add + w0 * sum_{k in nbr0(c)} rs0[k] + w1 * sum_{k in nbr1(c)} rs1[k]
// where rs_a = sum_{j in nbr_a(r)} K[j, :]  (rowsum, LDS-resident)
// MODE 0: apply relu_cov with svec.  MODE 1: plain + block-mean fp64 atomics.
template <int MODE>
__global__ __launch_bounds__(256) void conv_kernel(const float* K, const int* nnzc,
                                                   const int* colsa, const ushort* pcols,
                                                   const float* params, const float* svec,
                                                   float* Kout, double* sums) {
    __shared__ float rs0[NN + 8];
    __shared__ float rs1[NN + 8];
    __shared__ double red[512];
    int r = blockIdx.x;
    int t = threadIdx.x;
    float c_add = params[1], w0 = params[2], w1 = params[3];

    // ---- rowsum accumulation (register acc, coalesced row streams) ----
    {
        float4 acc0[4] = {{0,0,0,0},{0,0,0,0},{0,0,0,0},{0,0,0,0}};
        float4 acc1[4] = {{0,0,0,0},{0,0,0,0},{0,0,0,0},{0,0,0,0}};
        int cnt0 = nnzc[r], cnt1 = nnzc[NN + r];
        const int* crow0 = colsa + (size_t)r * MAXNNZ;
        const int* crow1 = colsa + (size_t)(NN + r) * MAXNNZ;
        for (int j = 0; j < cnt0; j++) {
            const float4* row = (const float4*)(K + (size_t)crow0[j] * NN);
            for (int q = 0; q < 4; q++) {
                float4 v = row[t + 256 * q];
                acc0[q].x += v.x; acc0[q].y += v.y; acc0[q].z += v.z; acc0[q].w += v.w;
            }
        }
        for (int j = 0; j < cnt1; j++) {
            const float4* row = (const float4*)(K + (size_t)crow1[j] * NN);
            for (int q = 0; q < 4; q++) {
                float4 v = row[t + 256 * q];
                acc1[q].x += v.x; acc1[q].y += v.y; acc1[q].z += v.z; acc1[q].w += v.w;
            }
        }
        for (int q = 0; q < 4; q++) {
            *(float4*)&rs0[4 * (t + 256 * q)] = acc0[q];
            *(float4*)&rs1[4 * (t + 256 * q)] = acc1[q];
        }
        if (t == 0) {
            for (int z = 0; z < 8; z++) { rs0[NN + z] = 0.f; rs1[NN + z] = 0.f; }
        }
    }
    __syncthreads();

    // ---- gather phase: 16 output cols per thread ----
    double d_lo = 0.0, d_hi = 0.0;
    float sr = (MODE == 0) ? svec[r] : 0.f;
    for (int u = 0; u < 16; u++) {
        int c = t + 256 * u;
        int basec = c & 2048;  // 0 for c<2048, 2048 otherwise
        uint4 L0 = *(const uint4*)&pcols[(size_t)c * 8];
        uint4 L1 = *(const uint4*)&pcols[(size_t)(NN + c) * 8];
        float ga = rs0[basec + (L0.x & 0xffff)] + rs0[basec + (L0.x >> 16)]
                 + rs0[basec + (L0.y & 0xffff)] + rs0[basec + (L0.y >> 16)]
                 + rs0[basec + (L0.z & 0xffff)] + rs0[basec + (L0.z >> 16)]
                 + rs0[basec + (L0.w & 0xffff)] + rs0[basec + (L0.w >> 16)];
        float gb = rs1[basec + (L1.x & 0xffff)] + rs1[basec + (L1.x >> 16)]
                 + rs1[basec + (L1.y & 0xffff)] + rs1[basec + (L1.y >> 16)]
                 + rs1[basec + (L1.z & 0xffff)] + rs1[basec + (L1.z >> 16)]
                 + rs1[basec + (L1.w & 0xffff)] + rs1[basec + (L1.w >> 16)];
        int c0n = nnzc[c], c1n = nnzc[NN + c];
        if (c0n > 8) {
            const int* cr = colsa + (size_t)c * MAXNNZ;
            for (int k = 8; k < c0n; k++) ga += rs0[cr[k]];
        }
        if (c1n > 8) {
            const int* cr = colsa + (size_t)(NN + c) * MAXNNZ;
            for (int k = 8; k < c1n; k++) gb += rs1[cr[k]];
        }
        float kv = c_add + w0 * ga + w1 * gb;
        if (MODE == 0) {
            const float PIF = 3.14159265358979323846f;
            const float INV2PI = 0.15915494309189535f;
            float p = sr * svec[c];
            float cc = kv / p;
            cc = fminf(fmaxf(cc, -1.f + 1e-6f), 1.f - 1e-6f);
            float th = acosf(cc);
            float sth = sqrtf(fmaxf(1.f - cc * cc, 0.f));
            kv = INV2PI * (sth + (PIF - th) * cc) * p;
        }
        Kout[(size_t)r * NN + c] = kv;
        if (MODE == 1) {
            if (c < 2048) d_lo += (double)kv; else d_hi += (double)kv;
        }
    }

    if (MODE == 1) {
        red[t] = d_lo;
        red[256 + t] = d_hi;
        __syncthreads();
        for (int off = 128; off; off >>= 1) {
            if (t < off) {
                red[t] += red[t + off];
                red[256 + t] += red[256 + t + off];
            }
            __syncthreads();
        }
        if (t == 0) {
            if (r < SS) {
                atomicAdd(&sums[0], red[0]);     // ss
                atomicAdd(&sums[1], red[256]);   // st (top-right only, matches ref)
            } else {
                atomicAdd(&sums[2], red[256]);   // tt
            }
        }
    }
}

// ---------------- final: gather + index_K scale ----------------
__global__ __launch_bounds__(256) void final_kernel(const float* K, const int* x1, const int* x2,
                                                    const double* sums, float* out) {
    size_t idx = (size_t)blockIdx.x * 256 + threadIdx.x;  // quad index
    int i = (int)(idx >> 10);
    int j4 = (int)(idx & 1023) << 2;
    const double invc = 1.0 / ((double)SS * (double)SS);
    float mss = (float)(sums[0] * invc);
    float mst = (float)(sums[1] * invc);
    float mtt = (float)(sums[2] * invc);
    int row = x1[i];
    float o[4];
    for (int j = 0; j < 4; j++) {
        int col = x2[j4 + j];
        float v = K[(size_t)row * NN + col];
        float m = (row < SS) ? (col < SS ? mss : mst) : (col < SS ? mst : mtt);
        o[j] = v * m;
    }
    float4 ov = {o[0], o[1], o[2], o[3]};
    *(float4*)&out[(size_t)i * NN + j4] = ov;
}

extern "C" void kernel_launch(void* const* d_in, const int* in_sizes, int n_in,
                              void* d_out, int out_size, void* d_ws, size_t ws_size,
                              hipStream_t stream) {
    const float* feat = (const float*)d_in[0];
    const float* adj  = (const float*)d_in[1];
    const float* rls  = (const float*)d_in[2];
    const float* rvw  = (const float*)d_in[3];
    const float* rsw  = (const float*)d_in[4];
    const float* rsb  = (const float*)d_in[5];
    const float* rsa  = (const float*)d_in[6];
    const float* rta  = (const float*)d_in[7];
    const int*   x1   = (const int*)d_in[8];
    const int*   x2   = (const int*)d_in[9];
    float* out = (float*)d_out;

    const size_t PNN = (size_t)NN * NN;
    char* w = (char*)d_ws;
    float*  params = (float*)(w + 0);            // 16 floats
    double* sums   = (double*)(w + 64);          // 3 doubles
    float*  xn     = (float*)(w + 128);          // 16 KB
    float*  svec   = (float*)(w + 128 + 16384);  // 16 KB
    int*    nnzc   = (int*)(w + 128 + 32768);    // 32 KB
    int*    colsa  = (int*)(w + 128 + 65536);    // 2 MiB
    ushort* pcols  = (ushort*)(w + 128 + 65536 + (size_t)NADJ * NN * MAXNNZ * 4);  // 128 KB
    ushort* xb     = (ushort*)(w + 128 + 65536 + (size_t)NADJ * NN * MAXNNZ * 4
                               + (size_t)NADJ * NN * 8 * 2);                        // 1 MiB
    size_t  big0   = ((size_t)(128 + 65536) + (size_t)NADJ * NN * MAXNNZ * 4
                      + (size_t)NADJ * NN * 8 * 2 + (size_t)NN * DD * 2 + 255) & ~(size_t)255;
    float* bufA = (float*)(w + big0);
    float* bufB = (ws_size >= big0 + 2 * PNN * 4) ? (bufA + PNN) : (float*)d_out;

    params_kernel<<<1, 64, 0, stream>>>(rls, rvw, rsw, rsb, rsa, rta, params, sums);
    xb_kernel<<<NN, 64, 0, stream>>>(feat, params, xb, xn);
    c0_mfma_kernel<<<dim3(NN / 128, NN / 128), 256, 0, stream>>>(xb, xn, bufA);
    extract_kernel<<<NADJ * NN, 64, 0, stream>>>(adj, nnzc, colsa, pcols);

    // svec = sqrt(diag(layer1 K)) from double-gather on C0
    diag1_kernel<<<NN / 4, 256, 0, stream>>>(bufA, nnzc, colsa, params, svec);

    // layer 1: C0 (bufA) -> relu_cov(K1) (bufB)
    conv_kernel<0><<<NN, 256, 0, stream>>>(bufA, nnzc, colsa, pcols, params, svec, bufB, sums);

    // layer 2: bufB -> K2 (bufA), with fused block sums
    conv_kernel<1><<<NN, 256, 0, stream>>>(bufB, nnzc, colsa, pcols, params, svec, bufA, sums);

    // final scale/gather
    final_kernel<<<16384, 256, 0, stream>>>(bufA, x1, x2, sums, out);
}

// Round 5
// 382.173 us; speedup vs baseline: 2.1565x; 1.1428x over previous
//
#include <hip/hip_runtime.h>
#include <math.h>

#define NN 4096
#define SS 2048
#define DD 128
#define NADJ 2
#define MAXNNZ 64

typedef short v8s __attribute__((ext_vector_type(8)));
typedef float v4f __attribute__((ext_vector_type(4)));

__device__ __forceinline__ float softplusf(float x) {
    if (x > 20.f) return x;
    if (x < -20.f) return expf(x);
    return log1pf(expf(x));
}

__device__ __forceinline__ ushort f2bf(float f) {
    unsigned int u = __float_as_uint(f);
    unsigned int r = (u + 0x7fff + ((u >> 16) & 1)) >> 16;  // RNE
    return (ushort)r;
}
__device__ __forceinline__ float bf2f(ushort h) {
    return __uint_as_float(((unsigned int)h) << 16);
}
__device__ __forceinline__ float blo(unsigned int u) { return __uint_as_float(u << 16); }
__device__ __forceinline__ float bhi(unsigned int u) { return __uint_as_float(u & 0xffff0000u); }

// ---------------- params + zero sums ----------------
__global__ void params_kernel(const float* rls, const float* rvw, const float* rsw,
                              const float* rsb, const float* rsa, const float* rta,
                              float* params, double* sums) {
    if (threadIdx.x == 0) {
        float ls = softplusf(rls[0]);
        float vw = softplusf(rvw[0]);
        float sw = softplusf(rsw[0]);
        float sb = softplusf(rsb[0]);
        float a0 = softplusf(rsa[0]) * softplusf(rta[0]);
        float a1 = softplusf(rsa[1]) * softplusf(rta[1]);
        float vw2 = vw * vw, sw2 = sw * sw, sb2 = sb * sb;
        params[0] = 1.f / ls;
        params[1] = vw2 * sb2 * (a0 + a1);  // c_add
        params[2] = vw2 * sw2 * a0;         // w0
        params[3] = vw2 * sw2 * a1;         // w1
        sums[0] = 0.0; sums[1] = 0.0; sums[2] = 0.0;
    }
}

// ---------------- xb = bf16(feat/ls), xn = ||xb_row||^2 ----------------
__global__ void xb_kernel(const float* feat, const float* params, ushort* xb, float* xn) {
    int r = blockIdx.x;
    int l = threadIdx.x;  // 64 lanes
    float inv_ls = params[0];
    ushort h0 = f2bf(feat[r * DD + l] * inv_ls);
    ushort h1 = f2bf(feat[r * DD + 64 + l] * inv_ls);
    xb[r * DD + l] = h0;
    xb[r * DD + 64 + l] = h1;
    float v0 = bf2f(h0), v1 = bf2f(h1);
    float s = v0 * v0 + v1 * v1;
    for (int off = 32; off; off >>= 1) s += __shfl_xor(s, off);
    if (l == 0) xn[r] = s;
}

// ---------------- C0 = bf16(exp(-0.5 * sqdist)) via bf16 MFMA ----------------
__global__ __launch_bounds__(256) void c0_mfma_kernel(const ushort* xb, const float* xn,
                                                      ushort* C0b) {
    __shared__ float xr[128], xc[128];
    int t = threadIdx.x;
    int r0 = blockIdx.y * 128, c0 = blockIdx.x * 128;
    if (t < 128) xr[t] = xn[r0 + t];
    else xc[t - 128] = xn[c0 + (t - 128)];
    __syncthreads();

    int w = t >> 6, l = t & 63;
    int wr = w >> 1, wc = w & 1;
    int lr = l & 15;          // fragment row/col within 16
    int lk = (l >> 4) * 8;    // k-chunk base
    const ushort* pa = xb + (size_t)(r0 + wr * 64 + lr) * DD + lk;
    const ushort* pb = xb + (size_t)(c0 + wc * 64 + lr) * DD + lk;

    v4f acc[4][4] = {};
    for (int ks = 0; ks < 4; ks++) {
        v8s a[4], b[4];
        for (int m = 0; m < 4; m++) a[m] = *(const v8s*)(pa + (size_t)m * 16 * DD + ks * 32);
        for (int n = 0; n < 4; n++) b[n] = *(const v8s*)(pb + (size_t)n * 16 * DD + ks * 32);
        for (int m = 0; m < 4; m++)
            for (int n = 0; n < 4; n++)
                acc[m][n] = __builtin_amdgcn_mfma_f32_16x16x32_bf16(a[m], b[n], acc[m][n], 0, 0, 0);
    }

    int rbase = wr * 64;
    int cbase = wc * 64;
    for (int m = 0; m < 4; m++) {
        for (int n = 0; n < 4; n++) {
            int ocol = cbase + n * 16 + lr;
            float xnc = xc[ocol];
            for (int j = 0; j < 4; j++) {
                int orow = rbase + m * 16 + (l >> 4) * 4 + j;
                float sq = xr[orow] + xnc - 2.f * acc[m][n][j];
                sq = fmaxf(sq, 0.f);
                C0b[(size_t)(r0 + orow) * NN + c0 + ocol] = f2bf(expf(-0.5f * sq));
            }
        }
    }
}

// ---------------- CSR extraction (block-masked), deterministic ----------------
__global__ void extract_kernel(const float* adj, int* nnzc, int* colsa, ushort* pcols) {
    __shared__ int sc[MAXNNZ];
    int b = blockIdx.x;        // a*NN + r
    int i = b >> 12;
    int r = b & (NN - 1);
    int lane = threadIdx.x;    // 64
    int base = (r < SS) ? 0 : SS;
    const float* arow = adj + ((size_t)i * NN + r) * NN + base;
    int cnt = 0;
    for (int it = 0; it < SS / 64; ++it) {
        int c = it * 64 + lane;
        float v = arow[c];
        unsigned long long m = __ballot(v != 0.f);
        if (v != 0.f) {
            int pos = cnt + __popcll(m & ((1ull << lane) - 1ull));
            if (pos < MAXNNZ) sc[pos] = c;  // relative col
        }
        cnt += __popcll(m);
    }
    if (cnt > MAXNNZ) cnt = MAXNNZ;
    __syncthreads();
    if (lane < cnt) colsa[(size_t)b * MAXNNZ + lane] = base + sc[lane];
    if (lane < 8) {
        int mn = cnt < 8 ? cnt : 8;
        ushort pad = (ushort)(4096 - base);  // base 0 -> 4096 ; base 2048 -> 2048
        pcols[(size_t)b * 8 + lane] = (lane < mn) ? (ushort)sc[lane] : pad;
    }
    if (lane == 0) nnzc[b] = cnt;
}

// ---------------- diag of layer-1 K -> svec (double gather on bf16 C0) ----------------
__global__ void diag1_kernel(const ushort* C0b, const int* nnzc, const int* colsa,
                             const float* params, float* svec) {
    int t = threadIdx.x;
    int r = blockIdx.x * 4 + (t >> 6);  // one wave per row
    int lane = t & 63;
    float c_add = params[1], w0 = params[2], w1 = params[3];
    float s = 0.f;
    for (int a = 0; a < 2; a++) {
        int b = a * NN + r;
        int cnt = nnzc[b];
        const int* crow = colsa + (size_t)b * MAXNNZ;
        int myk = crow[(lane < cnt) ? lane : 0];
        float wa = a ? w1 : w0;
        float acc = 0.f;
        for (int j = 0; j < cnt; j++) {
            int row = crow[j];
            if (lane < cnt) acc += bf2f(C0b[(size_t)row * NN + myk]);
        }
        s += wa * acc;
    }
    for (int off = 32; off; off >>= 1) s += __shfl_xor(s, off);
    if (lane == 0) {
        float d = c_add + s;
        svec[r] = sqrtf(fmaxf(d, 0.f)) + 1e-5f;
    }
}

// ---------------- fused conv: one output row per block, bf16 input ----------------
// MODE 0: relu_cov, output bf16.  MODE 1: plain, output fp32, block-mean fp64 atomics.
template <int MODE>
__global__ __launch_bounds__(256) void conv_kernel(const ushort* Kb, const int* nnzc,
                                                   const int* colsa, const ushort* pcols,
                                                   const float* params, const float* svec,
                                                   void* Kout_, double* sums) {
    __shared__ float rs0[NN + 8];
    __shared__ float rs1[NN + 8];
    __shared__ double red[512];
    int r = blockIdx.x;
    int t = threadIdx.x;
    float c_add = params[1], w0 = params[2], w1 = params[3];

    // ---- rowsum accumulation (fp32 register acc, coalesced bf16 row streams) ----
    {
        float acc0[16], acc1[16];
        #pragma unroll
        for (int e = 0; e < 16; e++) { acc0[e] = 0.f; acc1[e] = 0.f; }
        int cnt0 = nnzc[r], cnt1 = nnzc[NN + r];
        const int* crow0 = colsa + (size_t)r * MAXNNZ;
        const int* crow1 = colsa + (size_t)(NN + r) * MAXNNZ;
        for (int j = 0; j < cnt0; j++) {
            const uint4* row = (const uint4*)(Kb + (size_t)crow0[j] * NN);
            #pragma unroll
            for (int q = 0; q < 2; q++) {
                uint4 v = row[t + 256 * q];
                acc0[q * 8 + 0] += blo(v.x); acc0[q * 8 + 1] += bhi(v.x);
                acc0[q * 8 + 2] += blo(v.y); acc0[q * 8 + 3] += bhi(v.y);
                acc0[q * 8 + 4] += blo(v.z); acc0[q * 8 + 5] += bhi(v.z);
                acc0[q * 8 + 6] += blo(v.w); acc0[q * 8 + 7] += bhi(v.w);
            }
        }
        for (int j = 0; j < cnt1; j++) {
            const uint4* row = (const uint4*)(Kb + (size_t)crow1[j] * NN);
            #pragma unroll
            for (int q = 0; q < 2; q++) {
                uint4 v = row[t + 256 * q];
                acc1[q * 8 + 0] += blo(v.x); acc1[q * 8 + 1] += bhi(v.x);
                acc1[q * 8 + 2] += blo(v.y); acc1[q * 8 + 3] += bhi(v.y);
                acc1[q * 8 + 4] += blo(v.z); acc1[q * 8 + 5] += bhi(v.z);
                acc1[q * 8 + 6] += blo(v.w); acc1[q * 8 + 7] += bhi(v.w);
            }
        }
        #pragma unroll
        for (int q = 0; q < 2; q++) {
            int base = 8 * (t + 256 * q);
            *(float4*)&rs0[base]     = {acc0[q*8+0], acc0[q*8+1], acc0[q*8+2], acc0[q*8+3]};
            *(float4*)&rs0[base + 4] = {acc0[q*8+4], acc0[q*8+5], acc0[q*8+6], acc0[q*8+7]};
            *(float4*)&rs1[base]     = {acc1[q*8+0], acc1[q*8+1], acc1[q*8+2], acc1[q*8+3]};
            *(float4*)&rs1[base + 4] = {acc1[q*8+4], acc1[q*8+5], acc1[q*8+6], acc1[q*8+7]};
        }
        if (t == 0) {
            for (int z = 0; z < 8; z++) { rs0[NN + z] = 0.f; rs1[NN + z] = 0.f; }
        }
    }
    __syncthreads();

    // ---- gather phase: 16 output cols per thread ----
    double d_lo = 0.0, d_hi = 0.0;
    float sr = (MODE == 0) ? svec[r] : 0.f;
    ushort* out_b = (ushort*)Kout_;
    float* out_f = (float*)Kout_;
    for (int u = 0; u < 16; u++) {
        int c = t + 256 * u;
        int basec = c & 2048;  // 0 for c<2048, 2048 otherwise
        uint4 L0 = *(const uint4*)&pcols[(size_t)c * 8];
        uint4 L1 = *(const uint4*)&pcols[(size_t)(NN + c) * 8];
        float ga = rs0[basec + (L0.x & 0xffff)] + rs0[basec + (L0.x >> 16)]
                 + rs0[basec + (L0.y & 0xffff)] + rs0[basec + (L0.y >> 16)]
                 + rs0[basec + (L0.z & 0xffff)] + rs0[basec + (L0.z >> 16)]
                 + rs0[basec + (L0.w & 0xffff)] + rs0[basec + (L0.w >> 16)];
        float gb = rs1[basec + (L1.x & 0xffff)] + rs1[basec + (L1.x >> 16)]
                 + rs1[basec + (L1.y & 0xffff)] + rs1[basec + (L1.y >> 16)]
                 + rs1[basec + (L1.z & 0xffff)] + rs1[basec + (L1.z >> 16)]
                 + rs1[basec + (L1.w & 0xffff)] + rs1[basec + (L1.w >> 16)];
        int c0n = nnzc[c], c1n = nnzc[NN + c];
        if (c0n > 8) {
            const int* cr = colsa + (size_t)c * MAXNNZ;
            for (int k = 8; k < c0n; k++) ga += rs0[cr[k]];
        }
        if (c1n > 8) {
            const int* cr = colsa + (size_t)(NN + c) * MAXNNZ;
            for (int k = 8; k < c1n; k++) gb += rs1[cr[k]];
        }
        float kv = c_add + w0 * ga + w1 * gb;
        if (MODE == 0) {
            const float PIF = 3.14159265358979323846f;
            const float INV2PI = 0.15915494309189535f;
            float p = sr * svec[c];
            float cc = kv / p;
            cc = fminf(fmaxf(cc, -1.f + 1e-6f), 1.f - 1e-6f);
            float th = acosf(cc);
            float sth = sqrtf(fmaxf(1.f - cc * cc, 0.f));
            kv = INV2PI * (sth + (PIF - th) * cc) * p;
            out_b[(size_t)r * NN + c] = f2bf(kv);
        } else {
            out_f[(size_t)r * NN + c] = kv;
            if (c < 2048) d_lo += (double)kv; else d_hi += (double)kv;
        }
    }

    if (MODE == 1) {
        red[t] = d_lo;
        red[256 + t] = d_hi;
        __syncthreads();
        for (int off = 128; off; off >>= 1) {
            if (t < off) {
                red[t] += red[t + off];
                red[256 + t] += red[256 + t + off];
            }
            __syncthreads();
        }
        if (t == 0) {
            if (r < SS) {
                atomicAdd(&sums[0], red[0]);     // ss
                atomicAdd(&sums[1], red[256]);   // st
            } else {
                atomicAdd(&sums[2], red[256]);   // tt
            }
        }
    }
}

// ---------------- final: gather + index_K scale ----------------
__global__ __launch_bounds__(256) void final_kernel(const float* K, const int* x1, const int* x2,
                                                    const double* sums, float* out) {
    size_t idx = (size_t)blockIdx.x * 256 + threadIdx.x;  // quad index
    int i = (int)(idx >> 10);
    int j4 = (int)(idx & 1023) << 2;
    const double invc = 1.0 / ((double)SS * (double)SS);
    float mss = (float)(sums[0] * invc);
    float mst = (float)(sums[1] * invc);
    float mtt = (float)(sums[2] * invc);
    int row = x1[i];
    float o[4];
    for (int j = 0; j < 4; j++) {
        int col = x2[j4 + j];
        float v = K[(size_t)row * NN + col];
        float m = (row < SS) ? (col < SS ? mss : mst) : (col < SS ? mst : mtt);
        o[j] = v * m;
    }
    float4 ov = {o[0], o[1], o[2], o[3]};
    *(float4*)&out[(size_t)i * NN + j4] = ov;
}

extern "C" void kernel_launch(void* const* d_in, const int* in_sizes, int n_in,
                              void* d_out, int out_size, void* d_ws, size_t ws_size,
                              hipStream_t stream) {
    const float* feat = (const float*)d_in[0];
    const float* adj  = (const float*)d_in[1];
    const float* rls  = (const float*)d_in[2];
    const float* rvw  = (const float*)d_in[3];
    const float* rsw  = (const float*)d_in[4];
    const float* rsb  = (const float*)d_in[5];
    const float* rsa  = (const float*)d_in[6];
    const float* rta  = (const float*)d_in[7];
    const int*   x1   = (const int*)d_in[8];
    const int*   x2   = (const int*)d_in[9];
    float* out = (float*)d_out;

    const size_t PNN = (size_t)NN * NN;
    char* w = (char*)d_ws;
    float*  params = (float*)(w + 0);            // 16 floats
    double* sums   = (double*)(w + 64);          // 3 doubles
    float*  xn     = (float*)(w + 128);          // 16 KB
    float*  svec   = (float*)(w + 128 + 16384);  // 16 KB
    int*    nnzc   = (int*)(w + 128 + 32768);    // 32 KB
    int*    colsa  = (int*)(w + 128 + 65536);    // 2 MiB
    ushort* pcols  = (ushort*)(w + 128 + 65536 + (size_t)NADJ * NN * MAXNNZ * 4);  // 128 KB
    ushort* xb     = (ushort*)(w + 128 + 65536 + (size_t)NADJ * NN * MAXNNZ * 4
                               + (size_t)NADJ * NN * 8 * 2);                        // 1 MiB
    size_t  big0   = ((size_t)(128 + 65536) + (size_t)NADJ * NN * MAXNNZ * 4
                      + (size_t)NADJ * NN * 8 * 2 + (size_t)NN * DD * 2 + 255) & ~(size_t)255;
    ushort* cb0  = (ushort*)(w + big0);          // 32 MiB  bf16 C0
    ushort* kb1  = cb0 + PNN;                    // 32 MiB  bf16 relu(K1)
    float*  bufK2 = (ws_size >= big0 + 2 * PNN * 2 + PNN * 4)
                        ? (float*)(kb1 + PNN) : (float*)d_out;  // 64 MiB fp32 K2

    params_kernel<<<1, 64, 0, stream>>>(rls, rvw, rsw, rsb, rsa, rta, params, sums);
    xb_kernel<<<NN, 64, 0, stream>>>(feat, params, xb, xn);
    c0_mfma_kernel<<<dim3(NN / 128, NN / 128), 256, 0, stream>>>(xb, xn, cb0);
    extract_kernel<<<NADJ * NN, 64, 0, stream>>>(adj, nnzc, colsa, pcols);

    // svec = sqrt(diag(layer1 K)) from double-gather on C0
    diag1_kernel<<<NN / 4, 256, 0, stream>>>(cb0, nnzc, colsa, params, svec);

    // layer 1: C0 (bf16) -> relu_cov(K1) (bf16)
    conv_kernel<0><<<NN, 256, 0, stream>>>(cb0, nnzc, colsa, pcols, params, svec, kb1, sums);

    // layer 2: K1 (bf16) -> K2 (fp32), with fused block sums
    conv_kernel<1><<<NN, 256, 0, stream>>>(kb1, nnzc, colsa, pcols, params, svec, bufK2, sums);

    // final scale/gather
    final_kernel<<<16384, 256, 0, stream>>>(bufK2, x1, x2, sums, out);
}

// Round 6
// 294.425 us; speedup vs baseline: 2.7992x; 1.2980x over previous
//
#include <hip/hip_runtime.h>
#include <math.h>

#define NN 4096
#define SS 2048
#define DD 128
#define NADJ 2
#define MAXNNZ 64
#define HB 2048   // half-block width (cols per conv block)

typedef short v8s __attribute__((ext_vector_type(8)));
typedef float v4f __attribute__((ext_vector_type(4)));

__device__ __forceinline__ float softplusf(float x) {
    if (x > 20.f) return x;
    if (x < -20.f) return expf(x);
    return log1pf(expf(x));
}

__device__ __forceinline__ ushort f2bf(float f) {
    unsigned int u = __float_as_uint(f);
    unsigned int r = (u + 0x7fff + ((u >> 16) & 1)) >> 16;  // RNE
    return (ushort)r;
}
__device__ __forceinline__ float bf2f(ushort h) {
    return __uint_as_float(((unsigned int)h) << 16);
}
__device__ __forceinline__ float blo(unsigned int u) { return __uint_as_float(u << 16); }
__device__ __forceinline__ float bhi(unsigned int u) { return __uint_as_float(u & 0xffff0000u); }

// ---------------- params + zero sums ----------------
__global__ void params_kernel(const float* rls, const float* rvw, const float* rsw,
                              const float* rsb, const float* rsa, const float* rta,
                              float* params, double* sums) {
    if (threadIdx.x == 0) {
        float ls = softplusf(rls[0]);
        float vw = softplusf(rvw[0]);
        float sw = softplusf(rsw[0]);
        float sb = softplusf(rsb[0]);
        float a0 = softplusf(rsa[0]) * softplusf(rta[0]);
        float a1 = softplusf(rsa[1]) * softplusf(rta[1]);
        float vw2 = vw * vw, sw2 = sw * sw, sb2 = sb * sb;
        params[0] = 1.f / ls;
        params[1] = vw2 * sb2 * (a0 + a1);  // c_add
        params[2] = vw2 * sw2 * a0;         // w0
        params[3] = vw2 * sw2 * a1;         // w1
        sums[0] = 0.0; sums[1] = 0.0; sums[2] = 0.0;
    }
}

// ---------------- xb = bf16(feat/ls), xn = ||xb_row||^2 ----------------
__global__ void xb_kernel(const float* feat, const float* params, ushort* xb, float* xn) {
    int r = blockIdx.x;
    int l = threadIdx.x;  // 64 lanes
    float inv_ls = params[0];
    ushort h0 = f2bf(feat[r * DD + l] * inv_ls);
    ushort h1 = f2bf(feat[r * DD + 64 + l] * inv_ls);
    xb[r * DD + l] = h0;
    xb[r * DD + 64 + l] = h1;
    float v0 = bf2f(h0), v1 = bf2f(h1);
    float s = v0 * v0 + v1 * v1;
    for (int off = 32; off; off >>= 1) s += __shfl_xor(s, off);
    if (l == 0) xn[r] = s;
}

// ---------------- C0 = bf16(exp(-0.5 * sqdist)) via bf16 MFMA ----------------
__global__ __launch_bounds__(256) void c0_mfma_kernel(const ushort* xb, const float* xn,
                                                      ushort* C0b) {
    __shared__ float xr[128], xc[128];
    int t = threadIdx.x;
    int r0 = blockIdx.y * 128, c0 = blockIdx.x * 128;
    if (t < 128) xr[t] = xn[r0 + t];
    else xc[t - 128] = xn[c0 + (t - 128)];
    __syncthreads();

    int w = t >> 6, l = t & 63;
    int wr = w >> 1, wc = w & 1;
    int lr = l & 15;          // fragment row/col within 16
    int lk = (l >> 4) * 8;    // k-chunk base
    const ushort* pa = xb + (size_t)(r0 + wr * 64 + lr) * DD + lk;
    const ushort* pb = xb + (size_t)(c0 + wc * 64 + lr) * DD + lk;

    v4f acc[4][4] = {};
    for (int ks = 0; ks < 4; ks++) {
        v8s a[4], b[4];
        for (int m = 0; m < 4; m++) a[m] = *(const v8s*)(pa + (size_t)m * 16 * DD + ks * 32);
        for (int n = 0; n < 4; n++) b[n] = *(const v8s*)(pb + (size_t)n * 16 * DD + ks * 32);
        for (int m = 0; m < 4; m++)
            for (int n = 0; n < 4; n++)
                acc[m][n] = __builtin_amdgcn_mfma_f32_16x16x32_bf16(a[m], b[n], acc[m][n], 0, 0, 0);
    }

    int rbase = wr * 64;
    int cbase = wc * 64;
    for (int m = 0; m < 4; m++) {
        for (int n = 0; n < 4; n++) {
            int ocol = cbase + n * 16 + lr;
            float xnc = xc[ocol];
            for (int j = 0; j < 4; j++) {
                int orow = rbase + m * 16 + (l >> 4) * 4 + j;
                float sq = xr[orow] + xnc - 2.f * acc[m][n][j];
                sq = fmaxf(sq, 0.f);
                C0b[(size_t)(r0 + orow) * NN + c0 + ocol] = f2bf(expf(-0.5f * sq));
            }
        }
    }
}

// ---------------- CSR extraction (block-masked), deterministic ----------------
// colsa: absolute cols (int[64]); pcols: relative cols u16[8], pad = 2048 (zero slot).
__global__ void extract_kernel(const float* adj, int* nnzc, int* colsa, ushort* pcols) {
    __shared__ int sc[MAXNNZ];
    int b = blockIdx.x;        // a*NN + r
    int i = b >> 12;
    int r = b & (NN - 1);
    int lane = threadIdx.x;    // 64
    int base = (r < SS) ? 0 : SS;
    const float* arow = adj + ((size_t)i * NN + r) * NN + base;
    int cnt = 0;
    for (int it = 0; it < SS / 64; ++it) {
        int c = it * 64 + lane;
        float v = arow[c];
        unsigned long long m = __ballot(v != 0.f);
        if (v != 0.f) {
            int pos = cnt + __popcll(m & ((1ull << lane) - 1ull));
            if (pos < MAXNNZ) sc[pos] = c;  // relative col
        }
        cnt += __popcll(m);
    }
    if (cnt > MAXNNZ) cnt = MAXNNZ;
    __syncthreads();
    if (lane < cnt) colsa[(size_t)b * MAXNNZ + lane] = base + sc[lane];
    if (lane < 8) {
        int mn = cnt < 8 ? cnt : 8;
        pcols[(size_t)b * 8 + lane] = (lane < mn) ? (ushort)sc[lane] : (ushort)HB;
    }
    if (lane == 0) nnzc[b] = cnt;
}

// ---------------- diag of layer-1 K -> svec (double gather on bf16 C0) ----------------
__global__ void diag1_kernel(const ushort* C0b, const int* nnzc, const int* colsa,
                             const float* params, float* svec) {
    int t = threadIdx.x;
    int r = blockIdx.x * 4 + (t >> 6);  // one wave per row
    int lane = t & 63;
    float c_add = params[1], w0 = params[2], w1 = params[3];
    float s = 0.f;
    for (int a = 0; a < 2; a++) {
        int b = a * NN + r;
        int cnt = nnzc[b];
        const int* crow = colsa + (size_t)b * MAXNNZ;
        int myk = crow[(lane < cnt) ? lane : 0];
        float wa = a ? w1 : w0;
        float acc = 0.f;
        for (int j = 0; j < cnt; j++) {
            int row = crow[j];
            if (lane < cnt) acc += bf2f(C0b[(size_t)row * NN + myk]);
        }
        s += wa * acc;
    }
    for (int off = 32; off; off >>= 1) s += __shfl_xor(s, off);
    if (lane == 0) {
        float d = c_add + s;
        svec[r] = sqrtf(fmaxf(d, 0.f)) + 1e-5f;
    }
}

// ---------------- fused conv: one (row, col-half) per block, bf16 input ----------------
// Block (h, r): rowsum over K[j, h*2048 : h*2048+2048] for j in nbr(r) -> rs (fp32 LDS),
// then out[r, c] for the 2048 cols of half h via LDS gathers (indices are intra-block).
// MODE 0: relu_cov, output bf16.  MODE 1: plain, output fp32, block-mean fp64 atomics.
template <int MODE>
__global__ __launch_bounds__(256, 8) void conv_kernel(const ushort* Kb, const int* nnzc,
                                                      const int* colsa, const ushort* pcols,
                                                      const float* params, const float* svec,
                                                      void* Kout_, double* sums) {
    __shared__ float rs0[HB + 8];
    __shared__ float rs1[HB + 8];
    __shared__ double red[256];
    int h = blockIdx.x;        // col half: 0 or 1
    int r = blockIdx.y;
    int t = threadIdx.x;
    int cbase = h * HB;
    float c_add = params[1], w0 = params[2], w1 = params[3];

    // ---- rowsum accumulation: one uint4 (8 bf16) per thread per neighbor row ----
    {
        float acc0[8], acc1[8];
        #pragma unroll
        for (int e = 0; e < 8; e++) { acc0[e] = 0.f; acc1[e] = 0.f; }
        int cnt0 = nnzc[r], cnt1 = nnzc[NN + r];
        const int* crow0 = colsa + (size_t)r * MAXNNZ;
        const int* crow1 = colsa + (size_t)(NN + r) * MAXNNZ;
        for (int j = 0; j < cnt0; j++) {
            uint4 v = *(const uint4*)(Kb + (size_t)crow0[j] * NN + cbase + t * 8);
            acc0[0] += blo(v.x); acc0[1] += bhi(v.x);
            acc0[2] += blo(v.y); acc0[3] += bhi(v.y);
            acc0[4] += blo(v.z); acc0[5] += bhi(v.z);
            acc0[6] += blo(v.w); acc0[7] += bhi(v.w);
        }
        for (int j = 0; j < cnt1; j++) {
            uint4 v = *(const uint4*)(Kb + (size_t)crow1[j] * NN + cbase + t * 8);
            acc1[0] += blo(v.x); acc1[1] += bhi(v.x);
            acc1[2] += blo(v.y); acc1[3] += bhi(v.y);
            acc1[4] += blo(v.z); acc1[5] += bhi(v.z);
            acc1[6] += blo(v.w); acc1[7] += bhi(v.w);
        }
        *(float4*)&rs0[8 * t]     = {acc0[0], acc0[1], acc0[2], acc0[3]};
        *(float4*)&rs0[8 * t + 4] = {acc0[4], acc0[5], acc0[6], acc0[7]};
        *(float4*)&rs1[8 * t]     = {acc1[0], acc1[1], acc1[2], acc1[3]};
        *(float4*)&rs1[8 * t + 4] = {acc1[4], acc1[5], acc1[6], acc1[7]};
        if (t < 8) { rs0[HB + t] = 0.f; rs1[HB + t] = 0.f; }
    }
    __syncthreads();

    // ---- gather phase: 8 output cols per thread ----
    double dsum = 0.0;
    float sr = (MODE == 0) ? svec[r] : 0.f;
    ushort* out_b = (ushort*)Kout_;
    float* out_f = (float*)Kout_;
    for (int u = 0; u < 8; u++) {
        int c = cbase + t + 256 * u;
        uint4 L0 = *(const uint4*)&pcols[(size_t)c * 8];
        uint4 L1 = *(const uint4*)&pcols[(size_t)(NN + c) * 8];
        float ga = rs0[L0.x & 0xffff] + rs0[L0.x >> 16]
                 + rs0[L0.y & 0xffff] + rs0[L0.y >> 16]
                 + rs0[L0.z & 0xffff] + rs0[L0.z >> 16]
                 + rs0[L0.w & 0xffff] + rs0[L0.w >> 16];
        float gb = rs1[L1.x & 0xffff] + rs1[L1.x >> 16]
                 + rs1[L1.y & 0xffff] + rs1[L1.y >> 16]
                 + rs1[L1.z & 0xffff] + rs1[L1.z >> 16]
                 + rs1[L1.w & 0xffff] + rs1[L1.w >> 16];
        int c0n = nnzc[c], c1n = nnzc[NN + c];
        if (c0n > 8) {
            const int* cr = colsa + (size_t)c * MAXNNZ;
            for (int k = 8; k < c0n; k++) ga += rs0[cr[k] & (HB - 1)];
        }
        if (c1n > 8) {
            const int* cr = colsa + (size_t)(NN + c) * MAXNNZ;
            for (int k = 8; k < c1n; k++) gb += rs1[cr[k] & (HB - 1)];
        }
        float kv = c_add + w0 * ga + w1 * gb;
        if (MODE == 0) {
            const float PIF = 3.14159265358979323846f;
            const float INV2PI = 0.15915494309189535f;
            float p = sr * svec[c];
            float cc = kv / p;
            cc = fminf(fmaxf(cc, -1.f + 1e-6f), 1.f - 1e-6f);
            float th = acosf(cc);
            float sth = sqrtf(fmaxf(1.f - cc * cc, 0.f));
            kv = INV2PI * (sth + (PIF - th) * cc) * p;
            out_b[(size_t)r * NN + c] = f2bf(kv);
        } else {
            out_f[(size_t)r * NN + c] = kv;
            dsum += (double)kv;
        }
    }

    if (MODE == 1) {
        red[t] = dsum;
        __syncthreads();
        for (int off = 128; off; off >>= 1) {
            if (t < off) red[t] += red[t + off];
            __syncthreads();
        }
        if (t == 0) {
            // (r<S,h=0)->ss  (r<S,h=1)->st  (r>=S,h=1)->tt  (r>=S,h=0)-> skip
            if (r < SS) {
                if (h == 0) atomicAdd(&sums[0], red[0]);
                else        atomicAdd(&sums[1], red[0]);
            } else if (h == 1) {
                atomicAdd(&sums[2], red[0]);
            }
        }
    }
}

// ---------------- final: gather + index_K scale ----------------
__global__ __launch_bounds__(256) void final_kernel(const float* K, const int* x1, const int* x2,
                                                    const double* sums, float* out) {
    size_t idx = (size_t)blockIdx.x * 256 + threadIdx.x;  // quad index
    int i = (int)(idx >> 10);
    int j4 = (int)(idx & 1023) << 2;
    const double invc = 1.0 / ((double)SS * (double)SS);
    float mss = (float)(sums[0] * invc);
    float mst = (float)(sums[1] * invc);
    float mtt = (float)(sums[2] * invc);
    int row = x1[i];
    float o[4];
    for (int j = 0; j < 4; j++) {
        int col = x2[j4 + j];
        float v = K[(size_t)row * NN + col];
        float m = (row < SS) ? (col < SS ? mss : mst) : (col < SS ? mst : mtt);
        o[j] = v * m;
    }
    float4 ov = {o[0], o[1], o[2], o[3]};
    *(float4*)&out[(size_t)i * NN + j4] = ov;
}

extern "C" void kernel_launch(void* const* d_in, const int* in_sizes, int n_in,
                              void* d_out, int out_size, void* d_ws, size_t ws_size,
                              hipStream_t stream) {
    const float* feat = (const float*)d_in[0];
    const float* adj  = (const float*)d_in[1];
    const float* rls  = (const float*)d_in[2];
    const float* rvw  = (const float*)d_in[3];
    const float* rsw  = (const float*)d_in[4];
    const float* rsb  = (const float*)d_in[5];
    const float* rsa  = (const float*)d_in[6];
    const float* rta  = (const float*)d_in[7];
    const int*   x1   = (const int*)d_in[8];
    const int*   x2   = (const int*)d_in[9];
    float* out = (float*)d_out;

    const size_t PNN = (size_t)NN * NN;
    char* w = (char*)d_ws;
    float*  params = (float*)(w + 0);            // 16 floats
    double* sums   = (double*)(w + 64);          // 3 doubles
    float*  xn     = (float*)(w + 128);          // 16 KB
    float*  svec   = (float*)(w + 128 + 16384);  // 16 KB
    int*    nnzc   = (int*)(w + 128 + 32768);    // 32 KB
    int*    colsa  = (int*)(w + 128 + 65536);    // 2 MiB
    ushort* pcols  = (ushort*)(w + 128 + 65536 + (size_t)NADJ * NN * MAXNNZ * 4);  // 128 KB
    ushort* xb     = (ushort*)(w + 128 + 65536 + (size_t)NADJ * NN * MAXNNZ * 4
                               + (size_t)NADJ * NN * 8 * 2);                        // 1 MiB
    size_t  big0   = ((size_t)(128 + 65536) + (size_t)NADJ * NN * MAXNNZ * 4
                      + (size_t)NADJ * NN * 8 * 2 + (size_t)NN * DD * 2 + 255) & ~(size_t)255;
    ushort* cb0  = (ushort*)(w + big0);          // 32 MiB  bf16 C0
    ushort* kb1  = cb0 + PNN;                    // 32 MiB  bf16 relu(K1)
    float*  bufK2 = (ws_size >= big0 + 2 * PNN * 2 + PNN * 4)
                        ? (float*)(kb1 + PNN) : (float*)d_out;  // 64 MiB fp32 K2

    params_kernel<<<1, 64, 0, stream>>>(rls, rvw, rsw, rsb, rsa, rta, params, sums);
    xb_kernel<<<NN, 64, 0, stream>>>(feat, params, xb, xn);
    c0_mfma_kernel<<<dim3(NN / 128, NN / 128), 256, 0, stream>>>(xb, xn, cb0);
    extract_kernel<<<NADJ * NN, 64, 0, stream>>>(adj, nnzc, colsa, pcols);

    // svec = sqrt(diag(layer1 K)) from double-gather on C0
    diag1_kernel<<<NN / 4, 256, 0, stream>>>(cb0, nnzc, colsa, params, svec);

    // layer 1: C0 (bf16) -> relu_cov(K1) (bf16)
    conv_kernel<0><<<dim3(2, NN), 256, 0, stream>>>(cb0, nnzc, colsa, pcols, params, svec, kb1, sums);

    // layer 2: K1 (bf16) -> K2 (fp32), with fused block sums
    conv_kernel<1><<<dim3(2, NN), 256, 0, stream>>>(kb1, nnzc, colsa, pcols, params, svec, bufK2, sums);

    // final scale/gather
    final_kernel<<<16384, 256, 0, stream>>>(bufK2, x1, x2, sums, out);
}